// Round 1
// baseline (1105.107 us; speedup 1.0000x reference)
//
#include <hip/hip_runtime.h>

#define BATCH 2048
#define SQN 64
#define PCN 24
#define FEAT 16
#define HID 128
#define DOUT 256
#define TDIM 128
#define ADIM 4672
#define NSQT (BATCH*SQN)
#define NPCT (BATCH*PCN)
#define E_ADJ 420
#define E_ATT 40
#define E_ADJ_TOT (BATCH*E_ADJ)
#define E_ATT_TOT (BATCH*E_ATT)

#define KSQ_SMEM ((SQN*HID + PCN*HID + SQN*HID)*4 + (2*E_ADJ + 2*PCN)*4)

__device__ __forceinline__ float gelu_f(float x) {
    // jax.nn.gelu approximate=True: 0.5*x*(1+tanh(sqrt(2/pi)*(x+0.044715*x^3)))
    float z = 0.7978845608028654f * (x + 0.044715f * x * x * x);
    float e = __expf(2.0f * z);
    float t = 1.0f - 2.0f / (e + 1.0f);
    return 0.5f * x * (1.0f + t);
}

__device__ __forceinline__ float dot16(const float* xr, const float* wv) {
    const float4* x4 = (const float4*)xr;
    float4 x0 = x4[0], x1 = x4[1], x2 = x4[2], x3 = x4[3];
    return x0.x*wv[0] + x0.y*wv[1] + x0.z*wv[2] + x0.w*wv[3]
         + x1.x*wv[4] + x1.y*wv[5] + x1.z*wv[6] + x1.w*wv[7]
         + x2.x*wv[8] + x2.y*wv[9] + x2.z*wv[10]+ x2.w*wv[11]
         + x3.x*wv[12]+ x3.y*wv[13]+ x3.z*wv[14]+ x3.w*wv[15];
}

#define FMA44(ACCROW, A4, W0, W1, W2, W3) do { \
    ACCROW[0] += A4.x*W0.x + A4.y*W1.x + A4.z*W2.x + A4.w*W3.x; \
    ACCROW[1] += A4.x*W0.y + A4.y*W1.y + A4.z*W2.y + A4.w*W3.y; \
    ACCROW[2] += A4.x*W0.z + A4.y*W1.z + A4.z*W2.z + A4.w*W3.z; \
    ACCROW[3] += A4.x*W0.w + A4.y*W1.w + A4.z*W2.w + A4.w*W3.w; } while(0)

// ---------------------------------------------------------------------------
// ksq: per-batch square pipeline -> shared_out[b][0..255]  (= colsum(out_sq)/64)
// ---------------------------------------------------------------------------
__global__ __launch_bounds__(256, 2) void ksq_kernel(
    const float* __restrict__ x_sq, const float* __restrict__ x_pc,
    const float* __restrict__ W_in_sq, const float* __restrict__ b_in_sq,
    const float* __restrict__ W_in_pc, const float* __restrict__ b_in_pc,
    const float* __restrict__ W_adj, const float* __restrict__ W_occ,
    const float* __restrict__ W_out, const float* __restrict__ b_out,
    const int* __restrict__ ei_adj, const int* __restrict__ ei_occ,
    float* __restrict__ shared_out)
{
    extern __shared__ float smem[];
    float* h_sq = smem;                          // [64][128]
    float* h_pc = smem + SQN*HID;                // [24][128]
    float* dyn  = smem + SQN*HID + PCN*HID;      // aliased: xs/xp, AGG, red
    int*   eint = (int*)(smem + SQN*HID + PCN*HID + SQN*HID);
    int* e_src  = eint;
    int* e_dst  = eint + E_ADJ;
    int* o_srcp = eint + 2*E_ADJ;
    int* o_dst  = eint + 2*E_ADJ + PCN;

    const int t = threadIdx.x;
    const int b = blockIdx.x;

    // ---- P0: load edge indices + input feature tiles (xs/xp alias dyn) ----
    float* xs = dyn;             // [64][16]
    float* xp = dyn + SQN*FEAT;  // [24][16]
    for (int i = t; i < E_ADJ; i += 256) {
        e_src[i] = ei_adj[b*E_ADJ + i] - b*SQN;
        e_dst[i] = ei_adj[E_ADJ_TOT + b*E_ADJ + i] - b*SQN;
    }
    if (t < PCN) {
        o_srcp[t] = ei_occ[b*PCN + t] - b*PCN;
        o_dst[t]  = ei_occ[NPCT + b*PCN + t] - b*SQN;
    }
    for (int i = t; i < SQN*FEAT; i += 256) xs[i] = x_sq[b*SQN*FEAT + i];
    for (int i = t; i < PCN*FEAT; i += 256) xp[i] = x_pc[b*PCN*FEAT + i];
    __syncthreads();

    // ---- P1: h_sq = gelu(x_sq@W_in_sq+b), h_pc = gelu(x_pc@W_in_pc+b) ----
    {
        const int c = t & 127, half = t >> 7;
        float wv[16];
        #pragma unroll
        for (int k = 0; k < 16; ++k) wv[k] = W_in_sq[k*HID + c];
        float bb = b_in_sq[c];
        for (int r = half; r < SQN; r += 2)
            h_sq[r*HID + c] = gelu_f(bb + dot16(xs + r*FEAT, wv));
        #pragma unroll
        for (int k = 0; k < 16; ++k) wv[k] = W_in_pc[k*HID + c];
        bb = b_in_pc[c];
        for (int r = half; r < PCN; r += 2)
            h_pc[r*HID + c] = gelu_f(bb + dot16(xp + r*FEAT, wv));
    }
    __syncthreads();

    // ---- P2: zero AGG (overwrites xs/xp) ----
    float* AGG = dyn;   // [64][128]
    for (int i = t; i < SQN*HID; i += 256) AGG[i] = 0.0f;
    __syncthreads();

    // ---- P3: adjacency scatter (pre-W aggregation) ----
    {
        const int cc = t & 31, slot = t >> 5;
        for (int e0 = 0; e0 < E_ADJ; e0 += 8) {
            int e = e0 + slot;
            if (e < E_ADJ) {
                int s = e_src[e], d = e_dst[e];
                #pragma unroll
                for (int i = 0; i < 4; ++i)
                    atomicAdd(&AGG[d*HID + cc + 32*i], h_sq[s*HID + cc + 32*i]);
            }
        }
    }
    __syncthreads();

    // ---- P4: AGG = AGG @ W_adj (in place; wave w owns rows 16w..16w+15) ----
    {
        const int jq = t & 31, rg = t >> 5, j0 = jq*4;   // 32 col-quads, 8 row groups
        float acc[8][4];
        #pragma unroll
        for (int r = 0; r < 8; ++r) { acc[r][0]=0.f; acc[r][1]=0.f; acc[r][2]=0.f; acc[r][3]=0.f; }
        for (int kq = 0; kq < 32; ++kq) {
            float4 w0 = *(const float4*)(W_adj + (kq*4+0)*HID + j0);
            float4 w1 = *(const float4*)(W_adj + (kq*4+1)*HID + j0);
            float4 w2 = *(const float4*)(W_adj + (kq*4+2)*HID + j0);
            float4 w3 = *(const float4*)(W_adj + (kq*4+3)*HID + j0);
            #pragma unroll
            for (int rr = 0; rr < 8; ++rr) {
                float4 a = *(const float4*)(AGG + (rg*8+rr)*HID + kq*4);
                FMA44(acc[rr], a, w0, w1, w2, w3);
            }
        }
        #pragma unroll
        for (int rr = 0; rr < 8; ++rr)
            *(float4*)(AGG + (rg*8+rr)*HID + j0) =
                make_float4(acc[rr][0], acc[rr][1], acc[rr][2], acc[rr][3]);
    }
    __syncthreads();

    // ---- P5: occ edges: AGG[dst] += h_pc[src] @ W_occ (24 edges) ----
    {
        const int jq = t & 31, rg = t >> 5, j0 = jq*4;
        int sp[3], dd[3];
        #pragma unroll
        for (int ri = 0; ri < 3; ++ri) { int e = rg + ri*8; sp[ri] = o_srcp[e]; dd[ri] = o_dst[e]; }
        float acc[3][4];
        #pragma unroll
        for (int r = 0; r < 3; ++r) { acc[r][0]=0.f; acc[r][1]=0.f; acc[r][2]=0.f; acc[r][3]=0.f; }
        for (int kq = 0; kq < 32; ++kq) {
            float4 w0 = *(const float4*)(W_occ + (kq*4+0)*HID + j0);
            float4 w1 = *(const float4*)(W_occ + (kq*4+1)*HID + j0);
            float4 w2 = *(const float4*)(W_occ + (kq*4+2)*HID + j0);
            float4 w3 = *(const float4*)(W_occ + (kq*4+3)*HID + j0);
            #pragma unroll
            for (int ri = 0; ri < 3; ++ri) {
                float4 a = *(const float4*)(h_pc + sp[ri]*HID + kq*4);
                FMA44(acc[ri], a, w0, w1, w2, w3);
            }
        }
        #pragma unroll
        for (int ri = 0; ri < 3; ++ri)
            #pragma unroll
            for (int c = 0; c < 4; ++c)
                atomicAdd(&AGG[dd[ri]*HID + j0 + c], acc[ri][c]);
    }
    __syncthreads();

    // ---- P6: h_sq = gelu(h_sq + AGG) ----
    for (int i = t; i < SQN*HID/4; i += 256) {
        float4 h = ((float4*)h_sq)[i];
        float4 g = ((const float4*)AGG)[i];
        h.x = gelu_f(h.x + g.x); h.y = gelu_f(h.y + g.y);
        h.z = gelu_f(h.z + g.z); h.w = gelu_f(h.w + g.w);
        ((float4*)h_sq)[i] = h;
    }
    __syncthreads();

    // ---- P7: out_sq = gelu(h_sq2 @ W_out + b_out); colsum/64 -> shared ----
    {
        const int jq = t & 63, rg = t >> 6, j0 = jq*4;   // 64 col-quads (256 cols), 4 row groups
        float acc[16][4];
        #pragma unroll
        for (int r = 0; r < 16; ++r) { acc[r][0]=0.f; acc[r][1]=0.f; acc[r][2]=0.f; acc[r][3]=0.f; }
        for (int kq = 0; kq < 32; ++kq) {
            float4 w0 = *(const float4*)(W_out + (kq*4+0)*DOUT + j0);
            float4 w1 = *(const float4*)(W_out + (kq*4+1)*DOUT + j0);
            float4 w2 = *(const float4*)(W_out + (kq*4+2)*DOUT + j0);
            float4 w3 = *(const float4*)(W_out + (kq*4+3)*DOUT + j0);
            #pragma unroll
            for (int rr = 0; rr < 16; ++rr) {
                float4 a = *(const float4*)(h_sq + (rg*16+rr)*HID + kq*4);
                FMA44(acc[rr], a, w0, w1, w2, w3);
            }
        }
        float4 bo = *(const float4*)(b_out + j0);
        float cs0=0.f, cs1=0.f, cs2=0.f, cs3=0.f;
        #pragma unroll
        for (int rr = 0; rr < 16; ++rr) {
            cs0 += gelu_f(acc[rr][0] + bo.x);
            cs1 += gelu_f(acc[rr][1] + bo.y);
            cs2 += gelu_f(acc[rr][2] + bo.z);
            cs3 += gelu_f(acc[rr][3] + bo.w);
        }
        float* red = dyn;  // [4][256], AGG is dead
        *(float4*)(red + rg*DOUT + j0) = make_float4(cs0, cs1, cs2, cs3);
        __syncthreads();
        float s = red[t] + red[DOUT + t] + red[2*DOUT + t] + red[3*DOUT + t];
        shared_out[b*DOUT + t] = s * (1.0f/64.0f);
    }
}

// ---------------------------------------------------------------------------
// kpc: per-batch piece pipeline -> shared_out[b][*] += colsum(out_pc)/24
// ---------------------------------------------------------------------------
__global__ __launch_bounds__(256, 2) void kpc_kernel(
    const float* __restrict__ x_sq, const float* __restrict__ x_pc,
    const float* __restrict__ W_in_sq, const float* __restrict__ b_in_sq,
    const float* __restrict__ W_in_pc, const float* __restrict__ b_in_pc,
    const float* __restrict__ W_att, const float* __restrict__ W_def,
    const float* __restrict__ W_rev,
    const float* __restrict__ W_out, const float* __restrict__ b_out,
    const int* __restrict__ ei_att, const int* __restrict__ ei_def,
    const int* __restrict__ ei_rev,
    float* __restrict__ shared_out)
{
    __shared__ float h_pc[PCN*HID];
    __shared__ float S_att[PCN*HID];
    __shared__ float S_def[PCN*HID];
    __shared__ float S_rev[PCN*HID];
    __shared__ float xp[PCN*FEAT];
    __shared__ float xg[PCN*FEAT];
    __shared__ int ea_s[E_ATT], ea_d[E_ATT], ed_s[E_ATT], ed_d[E_ATT];
    __shared__ int rv_s[PCN], rv_d[PCN];
    __shared__ float red[4*DOUT];

    const int t = threadIdx.x;
    const int b = blockIdx.x;

    // ---- P0 ----
    if (t < E_ATT) {
        ea_s[t] = ei_att[b*E_ATT + t] - b*PCN;
        ea_d[t] = ei_att[E_ATT_TOT + b*E_ATT + t] - b*PCN;
        ed_s[t] = ei_def[b*E_ATT + t] - b*PCN;
        ed_d[t] = ei_def[E_ATT_TOT + b*E_ATT + t] - b*PCN;
    }
    if (t < PCN) {
        rv_s[t] = ei_rev[b*PCN + t];              // global square index
        rv_d[t] = ei_rev[NPCT + b*PCN + t] - b*PCN;
    }
    for (int i = t; i < PCN*FEAT; i += 256) xp[i] = x_pc[b*PCN*FEAT + i];
    __syncthreads();
    for (int i = t; i < PCN*FEAT; i += 256)
        xg[i] = x_sq[rv_s[i >> 4]*FEAT + (i & 15)];
    __syncthreads();

    // ---- P1: h_pc and S_rev (= h_sq rows gathered via rev edges) ----
    {
        const int c = t & 127, half = t >> 7;
        float wv[16];
        #pragma unroll
        for (int k = 0; k < 16; ++k) wv[k] = W_in_pc[k*HID + c];
        float bb = b_in_pc[c];
        for (int r = half; r < PCN; r += 2)
            h_pc[r*HID + c] = gelu_f(bb + dot16(xp + r*FEAT, wv));
        #pragma unroll
        for (int k = 0; k < 16; ++k) wv[k] = W_in_sq[k*HID + c];
        bb = b_in_sq[c];
        for (int r = half; r < PCN; r += 2)
            S_rev[rv_d[r]*HID + c] = gelu_f(bb + dot16(xg + r*FEAT, wv));
    }
    __syncthreads();

    // ---- P2: zero + att/def scatter ----
    for (int i = t; i < PCN*HID; i += 256) { S_att[i] = 0.0f; S_def[i] = 0.0f; }
    __syncthreads();
    {
        const int cc = t & 31, slot = t >> 5;
        for (int e0 = 0; e0 < E_ATT; e0 += 8) {
            int e = e0 + slot;
            int s = ea_s[e], d = ea_d[e];
            #pragma unroll
            for (int i = 0; i < 4; ++i)
                atomicAdd(&S_att[d*HID + cc + 32*i], h_pc[s*HID + cc + 32*i]);
            s = ed_s[e]; d = ed_d[e];
            #pragma unroll
            for (int i = 0; i < 4; ++i)
                atomicAdd(&S_def[d*HID + cc + 32*i], h_pc[s*HID + cc + 32*i]);
        }
    }
    __syncthreads();

    // ---- P3: h_pc = gelu(h_pc + S_att@W_att + S_def@W_def + S_rev@W_rev) ----
    {
        const int jq = t & 31, rg = t >> 5, j0 = jq*4;
        float acc[3][4];
        #pragma unroll
        for (int r = 0; r < 3; ++r) { acc[r][0]=0.f; acc[r][1]=0.f; acc[r][2]=0.f; acc[r][3]=0.f; }
        for (int kq = 0; kq < 32; ++kq) {
            float4 w0 = *(const float4*)(W_att + (kq*4+0)*HID + j0);
            float4 w1 = *(const float4*)(W_att + (kq*4+1)*HID + j0);
            float4 w2 = *(const float4*)(W_att + (kq*4+2)*HID + j0);
            float4 w3 = *(const float4*)(W_att + (kq*4+3)*HID + j0);
            #pragma unroll
            for (int ri = 0; ri < 3; ++ri) {
                float4 a = *(const float4*)(S_att + (rg + ri*8)*HID + kq*4);
                FMA44(acc[ri], a, w0, w1, w2, w3);
            }
        }
        for (int kq = 0; kq < 32; ++kq) {
            float4 w0 = *(const float4*)(W_def + (kq*4+0)*HID + j0);
            float4 w1 = *(const float4*)(W_def + (kq*4+1)*HID + j0);
            float4 w2 = *(const float4*)(W_def + (kq*4+2)*HID + j0);
            float4 w3 = *(const float4*)(W_def + (kq*4+3)*HID + j0);
            #pragma unroll
            for (int ri = 0; ri < 3; ++ri) {
                float4 a = *(const float4*)(S_def + (rg + ri*8)*HID + kq*4);
                FMA44(acc[ri], a, w0, w1, w2, w3);
            }
        }
        for (int kq = 0; kq < 32; ++kq) {
            float4 w0 = *(const float4*)(W_rev + (kq*4+0)*HID + j0);
            float4 w1 = *(const float4*)(W_rev + (kq*4+1)*HID + j0);
            float4 w2 = *(const float4*)(W_rev + (kq*4+2)*HID + j0);
            float4 w3 = *(const float4*)(W_rev + (kq*4+3)*HID + j0);
            #pragma unroll
            for (int ri = 0; ri < 3; ++ri) {
                float4 a = *(const float4*)(S_rev + (rg + ri*8)*HID + kq*4);
                FMA44(acc[ri], a, w0, w1, w2, w3);
            }
        }
        #pragma unroll
        for (int ri = 0; ri < 3; ++ri) {
            int p = rg + ri*8;
            float4 h = *(float4*)(h_pc + p*HID + j0);
            h.x = gelu_f(h.x + acc[ri][0]); h.y = gelu_f(h.y + acc[ri][1]);
            h.z = gelu_f(h.z + acc[ri][2]); h.w = gelu_f(h.w + acc[ri][3]);
            *(float4*)(h_pc + p*HID + j0) = h;
        }
    }
    __syncthreads();

    // ---- P4: out_pc = gelu(h_pc2 @ W_out + b_out); colsum/24 -> shared ----
    {
        const int jq = t & 63, rg = t >> 6, j0 = jq*4;
        float acc[6][4];
        #pragma unroll
        for (int r = 0; r < 6; ++r) { acc[r][0]=0.f; acc[r][1]=0.f; acc[r][2]=0.f; acc[r][3]=0.f; }
        for (int kq = 0; kq < 32; ++kq) {
            float4 w0 = *(const float4*)(W_out + (kq*4+0)*DOUT + j0);
            float4 w1 = *(const float4*)(W_out + (kq*4+1)*DOUT + j0);
            float4 w2 = *(const float4*)(W_out + (kq*4+2)*DOUT + j0);
            float4 w3 = *(const float4*)(W_out + (kq*4+3)*DOUT + j0);
            #pragma unroll
            for (int ri = 0; ri < 6; ++ri) {
                float4 a = *(const float4*)(h_pc + (rg + ri*4)*HID + kq*4);
                FMA44(acc[ri], a, w0, w1, w2, w3);
            }
        }
        float4 bo = *(const float4*)(b_out + j0);
        float cs0=0.f, cs1=0.f, cs2=0.f, cs3=0.f;
        #pragma unroll
        for (int ri = 0; ri < 6; ++ri) {
            cs0 += gelu_f(acc[ri][0] + bo.x);
            cs1 += gelu_f(acc[ri][1] + bo.y);
            cs2 += gelu_f(acc[ri][2] + bo.z);
            cs3 += gelu_f(acc[ri][3] + bo.w);
        }
        *(float4*)(red + rg*DOUT + j0) = make_float4(cs0, cs1, cs2, cs3);
        __syncthreads();
        float s = red[t] + red[DOUT + t] + red[2*DOUT + t] + red[3*DOUT + t];
        shared_out[b*DOUT + t] += s * (1.0f/24.0f);
    }
}

// ---------------------------------------------------------------------------
// khead: tpol = gelu(shared@W_pt+b_pt); value = tanh(gelu(shared@W_vt+b_vt)@W_vh+b_vh)
// ---------------------------------------------------------------------------
__global__ __launch_bounds__(256) void khead_kernel(
    const float* __restrict__ shared_in,
    const float* __restrict__ W_pt, const float* __restrict__ b_pt,
    const float* __restrict__ W_vt, const float* __restrict__ b_vt,
    const float* __restrict__ W_vh, const float* __restrict__ b_vh,
    float* __restrict__ tpol, float* __restrict__ out_value)
{
    __shared__ float sh[2*DOUT];
    __shared__ float vred[2*TDIM];
    const int t = threadIdx.x;
    const int hh = t >> 7, j = t & 127;
    const int b = blockIdx.x*2 + hh;
    for (int i = t; i < 2*DOUT; i += 256) sh[i] = shared_in[blockIdx.x*2*DOUT + i];
    __syncthreads();
    const float* s = sh + hh*DOUT;
    float ap = b_pt[j], av = b_vt[j];
    #pragma unroll 8
    for (int k = 0; k < DOUT; ++k) {
        float sv = s[k];
        ap += sv * W_pt[k*TDIM + j];
        av += sv * W_vt[k*TDIM + j];
    }
    tpol[b*TDIM + j] = gelu_f(ap);
    vred[hh*TDIM + j] = gelu_f(av) * W_vh[j];
    __syncthreads();
    for (int stp = 64; stp > 0; stp >>= 1) {
        if (j < stp) vred[hh*TDIM + j] += vred[hh*TDIM + j + stp];
        __syncthreads();
    }
    if (j == 0) out_value[b] = tanhf(vred[hh*TDIM] + b_vh[0]);
}

// ---------------------------------------------------------------------------
// kpol: policy = tpol @ W_ph + b_ph   ([2048,128]@[128,4672])
// ---------------------------------------------------------------------------
__global__ __launch_bounds__(256) void kpol_kernel(
    const float* __restrict__ tpol, const float* __restrict__ W_ph,
    const float* __restrict__ b_ph, float* __restrict__ pol)
{
    __shared__ float At[64*132];   // padded stride 132 to spread banks
    const int t = threadIdx.x;
    const int c0 = blockIdx.x * 64;
    const int r0 = blockIdx.y * 64;
    for (int i = t; i < 64*TDIM; i += 256)
        At[(i >> 7)*132 + (i & 127)] = tpol[(r0 + (i >> 7))*TDIM + (i & 127)];
    __syncthreads();
    const int tx = t & 15, ty = t >> 4;
    const int cc0 = c0 + tx*4;
    float acc[4][4];
    #pragma unroll
    for (int r = 0; r < 4; ++r) { acc[r][0]=0.f; acc[r][1]=0.f; acc[r][2]=0.f; acc[r][3]=0.f; }
    for (int kq = 0; kq < 32; ++kq) {
        float4 w0 = *(const float4*)(W_ph + (kq*4+0)*ADIM + cc0);
        float4 w1 = *(const float4*)(W_ph + (kq*4+1)*ADIM + cc0);
        float4 w2 = *(const float4*)(W_ph + (kq*4+2)*ADIM + cc0);
        float4 w3 = *(const float4*)(W_ph + (kq*4+3)*ADIM + cc0);
        #pragma unroll
        for (int rr = 0; rr < 4; ++rr) {
            float4 a = *(const float4*)(At + (ty*4+rr)*132 + kq*4);
            FMA44(acc[rr], a, w0, w1, w2, w3);
        }
    }
    float4 bp = *(const float4*)(b_ph + cc0);
    #pragma unroll
    for (int rr = 0; rr < 4; ++rr) {
        float4 o = make_float4(acc[rr][0]+bp.x, acc[rr][1]+bp.y,
                               acc[rr][2]+bp.z, acc[rr][3]+bp.w);
        *(float4*)(pol + (size_t)(r0+ty*4+rr)*ADIM + cc0) = o;
    }
}

// ---------------------------------------------------------------------------
extern "C" void kernel_launch(void* const* d_in, const int* in_sizes, int n_in,
                              void* d_out, int out_size, void* d_ws, size_t ws_size,
                              hipStream_t stream) {
    (void)in_sizes; (void)n_in; (void)out_size; (void)ws_size;
    const float* x_sq    = (const float*)d_in[0];
    const float* x_pc    = (const float*)d_in[1];
    const float* W_in_sq = (const float*)d_in[2];
    const float* b_in_sq = (const float*)d_in[3];
    const float* W_in_pc = (const float*)d_in[4];
    const float* b_in_pc = (const float*)d_in[5];
    const float* W_adj   = (const float*)d_in[6];
    const float* W_occ   = (const float*)d_in[7];
    const float* W_att   = (const float*)d_in[8];
    const float* W_def   = (const float*)d_in[9];
    const float* W_rev   = (const float*)d_in[10];
    const float* W_out   = (const float*)d_in[11];
    const float* b_out   = (const float*)d_in[12];
    const float* W_pt    = (const float*)d_in[13];
    const float* b_pt    = (const float*)d_in[14];
    const float* W_vt    = (const float*)d_in[15];
    const float* b_vt    = (const float*)d_in[16];
    const float* W_ph    = (const float*)d_in[17];
    const float* b_ph    = (const float*)d_in[18];
    const float* W_vh    = (const float*)d_in[19];
    const float* b_vh    = (const float*)d_in[20];
    const int* ei_adj    = (const int*)d_in[21];
    const int* ei_occ    = (const int*)d_in[22];
    const int* ei_att    = (const int*)d_in[23];
    const int* ei_def    = (const int*)d_in[24];
    const int* ei_rev    = (const int*)d_in[25];

    float* out = (float*)d_out;
    float* pol = out;
    float* val = out + (size_t)BATCH * ADIM;
    float* ws  = (float*)d_ws;
    float* shared_buf = ws;                    // [2048][256]
    float* tpol       = ws + BATCH * DOUT;     // [2048][128]

    hipFuncSetAttribute((const void*)ksq_kernel,
                        hipFuncAttributeMaxDynamicSharedMemorySize, KSQ_SMEM);

    ksq_kernel<<<BATCH, 256, KSQ_SMEM, stream>>>(
        x_sq, x_pc, W_in_sq, b_in_sq, W_in_pc, b_in_pc,
        W_adj, W_occ, W_out, b_out, ei_adj, ei_occ, shared_buf);
    kpc_kernel<<<BATCH, 256, 0, stream>>>(
        x_sq, x_pc, W_in_sq, b_in_sq, W_in_pc, b_in_pc,
        W_att, W_def, W_rev, W_out, b_out, ei_att, ei_def, ei_rev, shared_buf);
    khead_kernel<<<BATCH/2, 256, 0, stream>>>(
        shared_buf, W_pt, b_pt, W_vt, b_vt, W_vh, b_vh, tpol, val);
    kpol_kernel<<<dim3(ADIM/64, BATCH/64), 256, 0, stream>>>(
        tpol, W_ph, b_ph, pol);
}

// Round 2
// 1096.446 us; speedup vs baseline: 1.0079x; 1.0079x over previous
//
#include <hip/hip_runtime.h>

#define BATCH 2048
#define SQN 64
#define PCN 24
#define FEAT 16
#define HID 128
#define DOUT 256
#define TDIM 128
#define ADIM 4672
#define NSQT (BATCH*SQN)
#define NPCT (BATCH*PCN)
#define E_ADJ 420
#define E_ATT 40
#define E_ADJ_TOT (BATCH*E_ADJ)
#define E_ATT_TOT (BATCH*E_ATT)

#define KSQ_SMEM ((SQN*HID + PCN*HID + SQN*HID)*4 + (2*E_ADJ + 2*PCN)*4)

__device__ __forceinline__ float gelu_f(float x) {
    // jax.nn.gelu approximate=True: 0.5*x*(1+tanh(sqrt(2/pi)*(x+0.044715*x^3)))
    float z = 0.7978845608028654f * (x + 0.044715f * x * x * x);
    float e = __expf(2.0f * z);
    float t = 1.0f - 2.0f / (e + 1.0f);
    return 0.5f * x * (1.0f + t);
}

__device__ __forceinline__ float dot16(const float* xr, const float* wv) {
    const float4* x4 = (const float4*)xr;
    float4 x0 = x4[0], x1 = x4[1], x2 = x4[2], x3 = x4[3];
    return x0.x*wv[0] + x0.y*wv[1] + x0.z*wv[2] + x0.w*wv[3]
         + x1.x*wv[4] + x1.y*wv[5] + x1.z*wv[6] + x1.w*wv[7]
         + x2.x*wv[8] + x2.y*wv[9] + x2.z*wv[10]+ x2.w*wv[11]
         + x3.x*wv[12]+ x3.y*wv[13]+ x3.z*wv[14]+ x3.w*wv[15];
}

#define FMA44(ACCROW, A4, W0, W1, W2, W3) do { \
    (ACCROW)[0] += A4.x*W0.x + A4.y*W1.x + A4.z*W2.x + A4.w*W3.x; \
    (ACCROW)[1] += A4.x*W0.y + A4.y*W1.y + A4.z*W2.y + A4.w*W3.y; \
    (ACCROW)[2] += A4.x*W0.z + A4.y*W1.z + A4.z*W2.z + A4.w*W3.z; \
    (ACCROW)[3] += A4.x*W0.w + A4.y*W1.w + A4.z*W2.w + A4.w*W3.w; } while(0)

// ---------------------------------------------------------------------------
// ksq: per-batch square pipeline -> shared_out[b][0..255]  (= colsum(out_sq)/64)
// 512 threads (8 waves), 2 blocks/CU by LDS -> 4 waves/SIMD.
// ---------------------------------------------------------------------------
__global__ __launch_bounds__(512, 4) void ksq_kernel(
    const float* __restrict__ x_sq, const float* __restrict__ x_pc,
    const float* __restrict__ W_in_sq, const float* __restrict__ b_in_sq,
    const float* __restrict__ W_in_pc, const float* __restrict__ b_in_pc,
    const float* __restrict__ W_adj, const float* __restrict__ W_occ,
    const float* __restrict__ W_out, const float* __restrict__ b_out,
    const int* __restrict__ ei_adj, const int* __restrict__ ei_occ,
    float* __restrict__ shared_out)
{
    extern __shared__ float smem[];
    float* h_sq = smem;                          // [64][128]
    float* h_pc = smem + SQN*HID;                // [24][128]
    float* dyn  = smem + SQN*HID + PCN*HID;      // aliased: xs/xp, AGG, red
    int*   eint = (int*)(smem + SQN*HID + PCN*HID + SQN*HID);
    int* e_src  = eint;
    int* e_dst  = eint + E_ADJ;
    int* o_srcp = eint + 2*E_ADJ;
    int* o_dst  = eint + 2*E_ADJ + PCN;

    const int t = threadIdx.x;
    const int b = blockIdx.x;

    // ---- P0: load edge indices + input feature tiles (xs/xp alias dyn) ----
    float* xs = dyn;             // [64][16]
    float* xp = dyn + SQN*FEAT;  // [24][16]
    for (int i = t; i < E_ADJ; i += 512) {
        e_src[i] = ei_adj[b*E_ADJ + i] - b*SQN;
        e_dst[i] = ei_adj[E_ADJ_TOT + b*E_ADJ + i] - b*SQN;
    }
    if (t < PCN) {
        o_srcp[t] = ei_occ[b*PCN + t] - b*PCN;
        o_dst[t]  = ei_occ[NPCT + b*PCN + t] - b*SQN;
    }
    for (int i = t; i < SQN*FEAT; i += 512) xs[i] = x_sq[b*SQN*FEAT + i];
    for (int i = t; i < PCN*FEAT; i += 512) xp[i] = x_pc[b*PCN*FEAT + i];
    __syncthreads();

    // ---- P1: h_sq = gelu(x_sq@W_in_sq+b), h_pc = gelu(x_pc@W_in_pc+b) ----
    {
        const int c = t & 127, q = t >> 7;   // q in 0..3
        float wv[16];
        #pragma unroll
        for (int k = 0; k < 16; ++k) wv[k] = W_in_sq[k*HID + c];
        float bb = b_in_sq[c];
        for (int r = q; r < SQN; r += 4)
            h_sq[r*HID + c] = gelu_f(bb + dot16(xs + r*FEAT, wv));
        #pragma unroll
        for (int k = 0; k < 16; ++k) wv[k] = W_in_pc[k*HID + c];
        bb = b_in_pc[c];
        for (int r = q; r < PCN; r += 4)
            h_pc[r*HID + c] = gelu_f(bb + dot16(xp + r*FEAT, wv));
    }
    __syncthreads();

    // ---- P2: zero AGG (overwrites xs/xp) ----
    float* AGG = dyn;   // [64][128]
    for (int i = t; i < SQN*HID; i += 512) AGG[i] = 0.0f;
    __syncthreads();

    // ---- P3: adjacency scatter (pre-W aggregation) ----
    {
        const int cc = t & 31, slot = t >> 5;   // 16 slots of 32 lanes
        for (int e0 = 0; e0 < E_ADJ; e0 += 16) {
            int e = e0 + slot;
            if (e < E_ADJ) {
                int s = e_src[e], d = e_dst[e];
                #pragma unroll
                for (int i = 0; i < 4; ++i)
                    atomicAdd(&AGG[d*HID + cc + 32*i], h_sq[s*HID + cc + 32*i]);
            }
        }
    }
    __syncthreads();

    // ---- P4: AGG = AGG @ W_adj (in place; 32-lane group rg owns rows 4rg..4rg+3) ----
    {
        const int jq = t & 31, rg = t >> 5, j0 = jq*4;   // rg in 0..15
        float acc[4][4];
        #pragma unroll
        for (int r = 0; r < 4; ++r) { acc[r][0]=0.f; acc[r][1]=0.f; acc[r][2]=0.f; acc[r][3]=0.f; }
        #pragma unroll 2
        for (int kq = 0; kq < 32; ++kq) {
            float4 w0 = *(const float4*)(W_adj + (kq*4+0)*HID + j0);
            float4 w1 = *(const float4*)(W_adj + (kq*4+1)*HID + j0);
            float4 w2 = *(const float4*)(W_adj + (kq*4+2)*HID + j0);
            float4 w3 = *(const float4*)(W_adj + (kq*4+3)*HID + j0);
            #pragma unroll
            for (int rr = 0; rr < 4; ++rr) {
                float4 a = *(const float4*)(AGG + (rg*4+rr)*HID + kq*4);
                FMA44(acc[rr], a, w0, w1, w2, w3);
            }
        }
        #pragma unroll
        for (int rr = 0; rr < 4; ++rr)
            *(float4*)(AGG + (rg*4+rr)*HID + j0) =
                make_float4(acc[rr][0], acc[rr][1], acc[rr][2], acc[rr][3]);
    }
    __syncthreads();

    // ---- P5: occ edges: AGG[dst] += h_pc[src] @ W_occ (24 edges) ----
    {
        const int jq = t & 31, rg = t >> 5, j0 = jq*4;   // rg in 0..15
        const int e0 = rg, e1 = rg + 16;
        const bool has1 = (e1 < PCN);                    // rg < 8
        const int s0 = o_srcp[e0], d0 = o_dst[e0];
        const int s1 = has1 ? o_srcp[e1] : 0;
        const int d1 = has1 ? o_dst[e1]  : 0;
        float a0[4] = {0.f,0.f,0.f,0.f}, a1[4] = {0.f,0.f,0.f,0.f};
        #pragma unroll 2
        for (int kq = 0; kq < 32; ++kq) {
            float4 w0 = *(const float4*)(W_occ + (kq*4+0)*HID + j0);
            float4 w1 = *(const float4*)(W_occ + (kq*4+1)*HID + j0);
            float4 w2 = *(const float4*)(W_occ + (kq*4+2)*HID + j0);
            float4 w3 = *(const float4*)(W_occ + (kq*4+3)*HID + j0);
            float4 x0 = *(const float4*)(h_pc + s0*HID + kq*4);
            FMA44(a0, x0, w0, w1, w2, w3);
            float4 x1 = *(const float4*)(h_pc + s1*HID + kq*4);
            FMA44(a1, x1, w0, w1, w2, w3);
        }
        #pragma unroll
        for (int c = 0; c < 4; ++c) atomicAdd(&AGG[d0*HID + j0 + c], a0[c]);
        if (has1) {
            #pragma unroll
            for (int c = 0; c < 4; ++c) atomicAdd(&AGG[d1*HID + j0 + c], a1[c]);
        }
    }
    __syncthreads();

    // ---- P6: h_sq = gelu(h_sq + AGG) ----
    for (int i = t; i < SQN*HID/4; i += 512) {
        float4 h = ((float4*)h_sq)[i];
        float4 g = ((const float4*)AGG)[i];
        h.x = gelu_f(h.x + g.x); h.y = gelu_f(h.y + g.y);
        h.z = gelu_f(h.z + g.z); h.w = gelu_f(h.w + g.w);
        ((float4*)h_sq)[i] = h;
    }
    __syncthreads();

    // ---- P7: out_sq = gelu(h_sq2 @ W_out + b_out); colsum/64 -> shared ----
    // 32 col-groups of 8 cols x 16 row-groups of 4 rows: halves LDS A-read
    // amplification vs 4-col threads.
    {
        const int cg = t & 31, rg = t >> 5, j0 = cg*8;   // rg in 0..15
        float acc[4][8];
        #pragma unroll
        for (int r = 0; r < 4; ++r)
            #pragma unroll
            for (int c = 0; c < 8; ++c) acc[r][c] = 0.f;
        for (int kq = 0; kq < 32; ++kq) {
            float4 wa0 = *(const float4*)(W_out + (kq*4+0)*DOUT + j0);
            float4 wb0 = *(const float4*)(W_out + (kq*4+0)*DOUT + j0 + 4);
            float4 wa1 = *(const float4*)(W_out + (kq*4+1)*DOUT + j0);
            float4 wb1 = *(const float4*)(W_out + (kq*4+1)*DOUT + j0 + 4);
            float4 wa2 = *(const float4*)(W_out + (kq*4+2)*DOUT + j0);
            float4 wb2 = *(const float4*)(W_out + (kq*4+2)*DOUT + j0 + 4);
            float4 wa3 = *(const float4*)(W_out + (kq*4+3)*DOUT + j0);
            float4 wb3 = *(const float4*)(W_out + (kq*4+3)*DOUT + j0 + 4);
            #pragma unroll
            for (int rr = 0; rr < 4; ++rr) {
                float4 a = *(const float4*)(h_sq + (rg*4+rr)*HID + kq*4);
                FMA44(acc[rr],     a, wa0, wa1, wa2, wa3);
                FMA44((acc[rr]+4), a, wb0, wb1, wb2, wb3);
            }
        }
        float4 bo0 = *(const float4*)(b_out + j0);
        float4 bo1 = *(const float4*)(b_out + j0 + 4);
        float cs[8];
        #pragma unroll
        for (int c = 0; c < 8; ++c) cs[c] = 0.f;
        #pragma unroll
        for (int rr = 0; rr < 4; ++rr) {
            cs[0] += gelu_f(acc[rr][0] + bo0.x);
            cs[1] += gelu_f(acc[rr][1] + bo0.y);
            cs[2] += gelu_f(acc[rr][2] + bo0.z);
            cs[3] += gelu_f(acc[rr][3] + bo0.w);
            cs[4] += gelu_f(acc[rr][4] + bo1.x);
            cs[5] += gelu_f(acc[rr][5] + bo1.y);
            cs[6] += gelu_f(acc[rr][6] + bo1.z);
            cs[7] += gelu_f(acc[rr][7] + bo1.w);
        }
        float* red = dyn;  // [16][256], AGG is dead (last read in P6, barrier since)
        *(float4*)(red + rg*DOUT + j0)     = make_float4(cs[0], cs[1], cs[2], cs[3]);
        *(float4*)(red + rg*DOUT + j0 + 4) = make_float4(cs[4], cs[5], cs[6], cs[7]);
        __syncthreads();
        if (t < DOUT) {
            float s = 0.f;
            #pragma unroll
            for (int g = 0; g < 16; ++g) s += red[g*DOUT + t];
            shared_out[b*DOUT + t] = s * (1.0f/64.0f);
        }
    }
}

// ---------------------------------------------------------------------------
// kpc: per-batch piece pipeline -> shared_out[b][*] += colsum(out_pc)/24
// 512 threads (8 waves), 2 blocks/CU by LDS.
// ---------------------------------------------------------------------------
__global__ __launch_bounds__(512, 4) void kpc_kernel(
    const float* __restrict__ x_sq, const float* __restrict__ x_pc,
    const float* __restrict__ W_in_sq, const float* __restrict__ b_in_sq,
    const float* __restrict__ W_in_pc, const float* __restrict__ b_in_pc,
    const float* __restrict__ W_att, const float* __restrict__ W_def,
    const float* __restrict__ W_rev,
    const float* __restrict__ W_out, const float* __restrict__ b_out,
    const int* __restrict__ ei_att, const int* __restrict__ ei_def,
    const int* __restrict__ ei_rev,
    float* __restrict__ shared_out)
{
    __shared__ float h_pc[PCN*HID];
    __shared__ float S_att[PCN*HID];
    __shared__ float S_def[PCN*HID];
    __shared__ float S_rev[PCN*HID];
    __shared__ float xp[PCN*FEAT];
    __shared__ float xg[PCN*FEAT];
    __shared__ int ea_s[E_ATT], ea_d[E_ATT], ed_s[E_ATT], ed_d[E_ATT];
    __shared__ int rv_s[PCN], rv_d[PCN];
    __shared__ float red[8*DOUT];

    const int t = threadIdx.x;
    const int b = blockIdx.x;

    // ---- P0 ----
    if (t < E_ATT) {
        ea_s[t] = ei_att[b*E_ATT + t] - b*PCN;
        ea_d[t] = ei_att[E_ATT_TOT + b*E_ATT + t] - b*PCN;
        ed_s[t] = ei_def[b*E_ATT + t] - b*PCN;
        ed_d[t] = ei_def[E_ATT_TOT + b*E_ATT + t] - b*PCN;
    }
    if (t < PCN) {
        rv_s[t] = ei_rev[b*PCN + t];              // global square index
        rv_d[t] = ei_rev[NPCT + b*PCN + t] - b*PCN;
    }
    for (int i = t; i < PCN*FEAT; i += 512) xp[i] = x_pc[b*PCN*FEAT + i];
    __syncthreads();
    for (int i = t; i < PCN*FEAT; i += 512)
        xg[i] = x_sq[rv_s[i >> 4]*FEAT + (i & 15)];
    __syncthreads();

    // ---- P1: h_pc and S_rev (= h_sq rows gathered via rev edges) ----
    {
        const int c = t & 127, q = t >> 7;   // q in 0..3
        float wv[16];
        #pragma unroll
        for (int k = 0; k < 16; ++k) wv[k] = W_in_pc[k*HID + c];
        float bb = b_in_pc[c];
        for (int r = q; r < PCN; r += 4)
            h_pc[r*HID + c] = gelu_f(bb + dot16(xp + r*FEAT, wv));
        #pragma unroll
        for (int k = 0; k < 16; ++k) wv[k] = W_in_sq[k*HID + c];
        bb = b_in_sq[c];
        for (int r = q; r < PCN; r += 4)
            S_rev[rv_d[r]*HID + c] = gelu_f(bb + dot16(xg + r*FEAT, wv));
    }
    __syncthreads();

    // ---- P2: zero + att/def scatter ----
    for (int i = t; i < PCN*HID; i += 512) { S_att[i] = 0.0f; S_def[i] = 0.0f; }
    __syncthreads();
    {
        const int cc = t & 31, slot = t >> 5;   // 16 slots
        for (int e0 = 0; e0 < E_ATT; e0 += 16) {
            int e = e0 + slot;
            if (e < E_ATT) {
                int s = ea_s[e], d = ea_d[e];
                #pragma unroll
                for (int i = 0; i < 4; ++i)
                    atomicAdd(&S_att[d*HID + cc + 32*i], h_pc[s*HID + cc + 32*i]);
                s = ed_s[e]; d = ed_d[e];
                #pragma unroll
                for (int i = 0; i < 4; ++i)
                    atomicAdd(&S_def[d*HID + cc + 32*i], h_pc[s*HID + cc + 32*i]);
            }
        }
    }
    __syncthreads();

    // ---- P3: h_pc = gelu(h_pc + S_att@W_att + S_def@W_def + S_rev@W_rev) ----
    {
        const int jq = t & 31, rg = t >> 5, j0 = jq*4;   // rg in 0..15
        const int r0 = rg, r1 = rg + 16;
        const bool has1 = (r1 < PCN);                    // rg < 8
        const int r1c = has1 ? r1 : 0;
        float a0[4] = {0.f,0.f,0.f,0.f}, a1[4] = {0.f,0.f,0.f,0.f};
        #pragma unroll 2
        for (int kq = 0; kq < 32; ++kq) {
            float4 w0 = *(const float4*)(W_att + (kq*4+0)*HID + j0);
            float4 w1 = *(const float4*)(W_att + (kq*4+1)*HID + j0);
            float4 w2 = *(const float4*)(W_att + (kq*4+2)*HID + j0);
            float4 w3 = *(const float4*)(W_att + (kq*4+3)*HID + j0);
            float4 x0 = *(const float4*)(S_att + r0*HID + kq*4);
            FMA44(a0, x0, w0, w1, w2, w3);
            float4 x1 = *(const float4*)(S_att + r1c*HID + kq*4);
            FMA44(a1, x1, w0, w1, w2, w3);
        }
        #pragma unroll 2
        for (int kq = 0; kq < 32; ++kq) {
            float4 w0 = *(const float4*)(W_def + (kq*4+0)*HID + j0);
            float4 w1 = *(const float4*)(W_def + (kq*4+1)*HID + j0);
            float4 w2 = *(const float4*)(W_def + (kq*4+2)*HID + j0);
            float4 w3 = *(const float4*)(W_def + (kq*4+3)*HID + j0);
            float4 x0 = *(const float4*)(S_def + r0*HID + kq*4);
            FMA44(a0, x0, w0, w1, w2, w3);
            float4 x1 = *(const float4*)(S_def + r1c*HID + kq*4);
            FMA44(a1, x1, w0, w1, w2, w3);
        }
        #pragma unroll 2
        for (int kq = 0; kq < 32; ++kq) {
            float4 w0 = *(const float4*)(W_rev + (kq*4+0)*HID + j0);
            float4 w1 = *(const float4*)(W_rev + (kq*4+1)*HID + j0);
            float4 w2 = *(const float4*)(W_rev + (kq*4+2)*HID + j0);
            float4 w3 = *(const float4*)(W_rev + (kq*4+3)*HID + j0);
            float4 x0 = *(const float4*)(S_rev + r0*HID + kq*4);
            FMA44(a0, x0, w0, w1, w2, w3);
            float4 x1 = *(const float4*)(S_rev + r1c*HID + kq*4);
            FMA44(a1, x1, w0, w1, w2, w3);
        }
        float4 h = *(float4*)(h_pc + r0*HID + j0);
        h.x = gelu_f(h.x + a0[0]); h.y = gelu_f(h.y + a0[1]);
        h.z = gelu_f(h.z + a0[2]); h.w = gelu_f(h.w + a0[3]);
        *(float4*)(h_pc + r0*HID + j0) = h;
        if (has1) {
            float4 g = *(float4*)(h_pc + r1*HID + j0);
            g.x = gelu_f(g.x + a1[0]); g.y = gelu_f(g.y + a1[1]);
            g.z = gelu_f(g.z + a1[2]); g.w = gelu_f(g.w + a1[3]);
            *(float4*)(h_pc + r1*HID + j0) = g;
        }
    }
    __syncthreads();

    // ---- P4: out_pc = gelu(h_pc2 @ W_out + b_out); colsum/24 -> shared ----
    {
        const int jq = t & 63, rg = t >> 6, j0 = jq*4;   // rg in 0..7, rows rg,rg+8,rg+16
        float acc[3][4];
        #pragma unroll
        for (int r = 0; r < 3; ++r) { acc[r][0]=0.f; acc[r][1]=0.f; acc[r][2]=0.f; acc[r][3]=0.f; }
        for (int kq = 0; kq < 32; ++kq) {
            float4 w0 = *(const float4*)(W_out + (kq*4+0)*DOUT + j0);
            float4 w1 = *(const float4*)(W_out + (kq*4+1)*DOUT + j0);
            float4 w2 = *(const float4*)(W_out + (kq*4+2)*DOUT + j0);
            float4 w3 = *(const float4*)(W_out + (kq*4+3)*DOUT + j0);
            #pragma unroll
            for (int ri = 0; ri < 3; ++ri) {
                float4 a = *(const float4*)(h_pc + (rg + ri*8)*HID + kq*4);
                FMA44(acc[ri], a, w0, w1, w2, w3);
            }
        }
        float4 bo = *(const float4*)(b_out + j0);
        float cs0=0.f, cs1=0.f, cs2=0.f, cs3=0.f;
        #pragma unroll
        for (int ri = 0; ri < 3; ++ri) {
            cs0 += gelu_f(acc[ri][0] + bo.x);
            cs1 += gelu_f(acc[ri][1] + bo.y);
            cs2 += gelu_f(acc[ri][2] + bo.z);
            cs3 += gelu_f(acc[ri][3] + bo.w);
        }
        *(float4*)(red + rg*DOUT + j0) = make_float4(cs0, cs1, cs2, cs3);
        __syncthreads();
        if (t < DOUT) {
            float s = 0.f;
            #pragma unroll
            for (int g = 0; g < 8; ++g) s += red[g*DOUT + t];
            shared_out[b*DOUT + t] += s * (1.0f/24.0f);
        }
    }
}

// ---------------------------------------------------------------------------
// khead: tpol = gelu(shared@W_pt+b_pt); value = tanh(gelu(shared@W_vt+b_vt)@W_vh+b_vh)
// ---------------------------------------------------------------------------
__global__ __launch_bounds__(256) void khead_kernel(
    const float* __restrict__ shared_in,
    const float* __restrict__ W_pt, const float* __restrict__ b_pt,
    const float* __restrict__ W_vt, const float* __restrict__ b_vt,
    const float* __restrict__ W_vh, const float* __restrict__ b_vh,
    float* __restrict__ tpol, float* __restrict__ out_value)
{
    __shared__ float sh[2*DOUT];
    __shared__ float vred[2*TDIM];
    const int t = threadIdx.x;
    const int hh = t >> 7, j = t & 127;
    const int b = blockIdx.x*2 + hh;
    for (int i = t; i < 2*DOUT; i += 256) sh[i] = shared_in[blockIdx.x*2*DOUT + i];
    __syncthreads();
    const float* s = sh + hh*DOUT;
    float ap = b_pt[j], av = b_vt[j];
    #pragma unroll 8
    for (int k = 0; k < DOUT; ++k) {
        float sv = s[k];
        ap += sv * W_pt[k*TDIM + j];
        av += sv * W_vt[k*TDIM + j];
    }
    tpol[b*TDIM + j] = gelu_f(ap);
    vred[hh*TDIM + j] = gelu_f(av) * W_vh[j];
    __syncthreads();
    for (int stp = 64; stp > 0; stp >>= 1) {
        if (j < stp) vred[hh*TDIM + j] += vred[hh*TDIM + j + stp];
        __syncthreads();
    }
    if (j == 0) out_value[b] = tanhf(vred[hh*TDIM] + b_vh[0]);
}

// ---------------------------------------------------------------------------
// kpol: policy = tpol @ W_ph + b_ph   ([2048,128]@[128,4672])
// ---------------------------------------------------------------------------
__global__ __launch_bounds__(256) void kpol_kernel(
    const float* __restrict__ tpol, const float* __restrict__ W_ph,
    const float* __restrict__ b_ph, float* __restrict__ pol)
{
    __shared__ float At[64*132];   // padded stride 132 to spread banks
    const int t = threadIdx.x;
    const int c0 = blockIdx.x * 64;
    const int r0 = blockIdx.y * 64;
    for (int i = t; i < 64*TDIM; i += 256)
        At[(i >> 7)*132 + (i & 127)] = tpol[(r0 + (i >> 7))*TDIM + (i & 127)];
    __syncthreads();
    const int tx = t & 15, ty = t >> 4;
    const int cc0 = c0 + tx*4;
    float acc[4][4];
    #pragma unroll
    for (int r = 0; r < 4; ++r) { acc[r][0]=0.f; acc[r][1]=0.f; acc[r][2]=0.f; acc[r][3]=0.f; }
    #pragma unroll 2
    for (int kq = 0; kq < 32; ++kq) {
        float4 w0 = *(const float4*)(W_ph + (kq*4+0)*ADIM + cc0);
        float4 w1 = *(const float4*)(W_ph + (kq*4+1)*ADIM + cc0);
        float4 w2 = *(const float4*)(W_ph + (kq*4+2)*ADIM + cc0);
        float4 w3 = *(const float4*)(W_ph + (kq*4+3)*ADIM + cc0);
        #pragma unroll
        for (int rr = 0; rr < 4; ++rr) {
            float4 a = *(const float4*)(At + (ty*4+rr)*132 + kq*4);
            FMA44(acc[rr], a, w0, w1, w2, w3);
        }
    }
    float4 bp = *(const float4*)(b_ph + cc0);
    #pragma unroll
    for (int rr = 0; rr < 4; ++rr) {
        float4 o = make_float4(acc[rr][0]+bp.x, acc[rr][1]+bp.y,
                               acc[rr][2]+bp.z, acc[rr][3]+bp.w);
        *(float4*)(pol + (size_t)(r0+ty*4+rr)*ADIM + cc0) = o;
    }
}

// ---------------------------------------------------------------------------
extern "C" void kernel_launch(void* const* d_in, const int* in_sizes, int n_in,
                              void* d_out, int out_size, void* d_ws, size_t ws_size,
                              hipStream_t stream) {
    (void)in_sizes; (void)n_in; (void)out_size; (void)ws_size;
    const float* x_sq    = (const float*)d_in[0];
    const float* x_pc    = (const float*)d_in[1];
    const float* W_in_sq = (const float*)d_in[2];
    const float* b_in_sq = (const float*)d_in[3];
    const float* W_in_pc = (const float*)d_in[4];
    const float* b_in_pc = (const float*)d_in[5];
    const float* W_adj   = (const float*)d_in[6];
    const float* W_occ   = (const float*)d_in[7];
    const float* W_att   = (const float*)d_in[8];
    const float* W_def   = (const float*)d_in[9];
    const float* W_rev   = (const float*)d_in[10];
    const float* W_out   = (const float*)d_in[11];
    const float* b_out   = (const float*)d_in[12];
    const float* W_pt    = (const float*)d_in[13];
    const float* b_pt    = (const float*)d_in[14];
    const float* W_vt    = (const float*)d_in[15];
    const float* b_vt    = (const float*)d_in[16];
    const float* W_ph    = (const float*)d_in[17];
    const float* b_ph    = (const float*)d_in[18];
    const float* W_vh    = (const float*)d_in[19];
    const float* b_vh    = (const float*)d_in[20];
    const int* ei_adj    = (const int*)d_in[21];
    const int* ei_occ    = (const int*)d_in[22];
    const int* ei_att    = (const int*)d_in[23];
    const int* ei_def    = (const int*)d_in[24];
    const int* ei_rev    = (const int*)d_in[25];

    float* out = (float*)d_out;
    float* pol = out;
    float* val = out + (size_t)BATCH * ADIM;
    float* ws  = (float*)d_ws;
    float* shared_buf = ws;                    // [2048][256]
    float* tpol       = ws + BATCH * DOUT;     // [2048][128]

    hipFuncSetAttribute((const void*)ksq_kernel,
                        hipFuncAttributeMaxDynamicSharedMemorySize, KSQ_SMEM);

    ksq_kernel<<<BATCH, 512, KSQ_SMEM, stream>>>(
        x_sq, x_pc, W_in_sq, b_in_sq, W_in_pc, b_in_pc,
        W_adj, W_occ, W_out, b_out, ei_adj, ei_occ, shared_buf);
    kpc_kernel<<<BATCH, 512, 0, stream>>>(
        x_sq, x_pc, W_in_sq, b_in_sq, W_in_pc, b_in_pc,
        W_att, W_def, W_rev, W_out, b_out, ei_att, ei_def, ei_rev, shared_buf);
    khead_kernel<<<BATCH/2, 256, 0, stream>>>(
        shared_buf, W_pt, b_pt, W_vt, b_vt, W_vh, b_vh, tpol, val);
    kpol_kernel<<<dim3(ADIM/64, BATCH/64), 256, 0, stream>>>(
        tpol, W_ph, b_ph, pol);
}

// Round 4
// 263.800 us; speedup vs baseline: 4.1892x; 4.1564x over previous
//
#include <hip/hip_runtime.h>

#define BATCH 2048
#define SQN 64
#define PCN 24
#define FEAT 16
#define HID 128
#define DOUT 256
#define TDIM 128
#define ADIM 4672
#define NSQT (BATCH*SQN)
#define NPCT (BATCH*PCN)
#define E_ADJ 420
#define E_ATT 40
#define E_ADJ_TOT (BATCH*E_ADJ)
#define E_ATT_TOT (BATCH*E_ATT)

typedef unsigned short u16;
typedef unsigned int u32;
typedef __attribute__((ext_vector_type(8))) short bf16x8;
typedef __attribute__((ext_vector_type(8))) unsigned short u16x8;
typedef __attribute__((ext_vector_type(4))) float f32x4;

// ---- weight fragment buffer offsets (u16 units), hi/lo split ----
#define OFF_WADJ_H 0
#define OFF_WADJ_L 16384
#define OFF_WOCC_H 32768
#define OFF_WOCC_L 49152
#define OFF_WATT_H 65536
#define OFF_WATT_L 81920
#define OFF_WDEF_H 98304
#define OFF_WDEF_L 114688
#define OFF_WREV_H 131072
#define OFF_WREV_L 147456
#define OFF_WOUT_H 163840
#define OFF_WOUT_L 196608
#define OFF_WPH_H  229376
#define OFF_WPH_L  827392

// ---- k_sq dynamic LDS layout (bytes) ----
#define HS_OFF   0        // [64][512B] fp32 swizzled
#define AH_OFF   32768    // [64][256B] bf16 swizzled
#define AL_OFF   49152    // [64][256B] bf16 swizzled
#define HP_OFF   65536    // [24][256B] bf16 swizzled (hi only; occ path)
#define EPK_OFF  71680    // 420 packed (src | dst<<16)
#define SRT_OFF  73360    // 420
#define RSA_OFF  75040    // 65
#define CURA_OFF 75300    // 64
#define CNTA_OFF 75556    // 64
#define RSO_OFF  75812    // 65
#define CURO_OFF 76072    // 64
#define CNTO_OFF 76328    // 64
#define SRTO_OFF 76584    // 24
#define OPK_OFF  76680    // 24
#define KSQ_SMEM 76776

__device__ __forceinline__ float gelu_f(float x) {
    float z = 0.7978845608028654f * (x + 0.044715f * x * x * x);
    float e = __expf(2.0f * z);
    float t = 1.0f - 2.0f / (e + 1.0f);
    return 0.5f * x * (1.0f + t);
}
__device__ __forceinline__ u16 f2b(float x) {   // fp32 -> bf16 RNE
    u32 u = __float_as_uint(x);
    u += 0x7fffu + ((u >> 16) & 1u);
    return (u16)(u >> 16);
}
__device__ __forceinline__ float b2f(u16 h) { return __uint_as_float(((u32)h) << 16); }
__device__ __forceinline__ void split2(float x, u16& h, u16& l) {
    u16 hh = f2b(x); h = hh; l = f2b(x - b2f(hh));
}
__device__ __forceinline__ float dot16(const float* xr, const float* wv) {
    const float4* x4 = (const float4*)xr;
    float4 x0 = x4[0], x1 = x4[1], x2 = x4[2], x3 = x4[3];
    return x0.x*wv[0] + x0.y*wv[1] + x0.z*wv[2] + x0.w*wv[3]
         + x1.x*wv[4] + x1.y*wv[5] + x1.z*wv[6] + x1.w*wv[7]
         + x2.x*wv[8] + x2.y*wv[9] + x2.z*wv[10]+ x2.w*wv[11]
         + x3.x*wv[12]+ x3.y*wv[13]+ x3.z*wv[14]+ x3.w*wv[15];
}
__device__ __forceinline__ f32x4 MFMA(bf16x8 a, bf16x8 b, f32x4 c) {
    return __builtin_amdgcn_mfma_f32_16x16x32_bf16(a, b, c, 0, 0, 0);
}

// GEMM over K=128, 2 n-tiles per wave, split-bf16 3-term.
template<int RT>
__device__ __forceinline__ void gemm_2nt(
    const unsigned char* Ah, const unsigned char* Al,
    const u16* __restrict__ wh, const u16* __restrict__ wl,
    int w, int lane, int g, int lr, f32x4 (&c)[2][RT])
{
    const int sw = lr << 4;
    #pragma unroll
    for (int ks = 0; ks < 4; ++ks) {
        bf16x8 bh0 = *(const bf16x8*)(wh + (((w*2+0)*4 + ks)*64 + lane)*8);
        bf16x8 bl0 = *(const bf16x8*)(wl + (((w*2+0)*4 + ks)*64 + lane)*8);
        bf16x8 bh1 = *(const bf16x8*)(wh + (((w*2+1)*4 + ks)*64 + lane)*8);
        bf16x8 bl1 = *(const bf16x8*)(wl + (((w*2+1)*4 + ks)*64 + lane)*8);
        const int ko = ks*64 + g*16;
        #pragma unroll
        for (int rt = 0; rt < RT; ++rt) {
            const int ro = (rt*16 + lr)*256 + (ko ^ sw);
            bf16x8 ah = *(const bf16x8*)(Ah + ro);
            bf16x8 al = *(const bf16x8*)(Al + ro);
            c[0][rt] = MFMA(ah, bh0, c[0][rt]);
            c[0][rt] = MFMA(al, bh0, c[0][rt]);
            c[0][rt] = MFMA(ah, bl0, c[0][rt]);
            c[1][rt] = MFMA(ah, bh1, c[1][rt]);
            c[1][rt] = MFMA(al, bh1, c[1][rt]);
            c[1][rt] = MFMA(ah, bl1, c[1][rt]);
        }
    }
}

// GEMM over K=128 -> 256 cols (W_out), 4 n-tiles per wave, split-bf16 3-term.
template<int RT>
__device__ __forceinline__ void gemm_4nt(
    const unsigned char* Ah, const unsigned char* Al,
    const u16* __restrict__ wh, const u16* __restrict__ wl,
    int w, int lane, int g, int lr, f32x4 (&c)[4][RT])
{
    const int sw = lr << 4;
    #pragma unroll
    for (int ks = 0; ks < 4; ++ks) {
        bf16x8 ah[RT], al[RT];
        const int ko = ks*64 + g*16;
        #pragma unroll
        for (int rt = 0; rt < RT; ++rt) {
            const int ro = (rt*16 + lr)*256 + (ko ^ sw);
            ah[rt] = *(const bf16x8*)(Ah + ro);
            al[rt] = *(const bf16x8*)(Al + ro);
        }
        #pragma unroll
        for (int ntl = 0; ntl < 4; ++ntl) {
            bf16x8 bh = *(const bf16x8*)(wh + (((w*4+ntl)*4 + ks)*64 + lane)*8);
            bf16x8 bl = *(const bf16x8*)(wl + (((w*4+ntl)*4 + ks)*64 + lane)*8);
            #pragma unroll
            for (int rt = 0; rt < RT; ++rt) {
                c[ntl][rt] = MFMA(ah[rt], bh, c[ntl][rt]);
                c[ntl][rt] = MFMA(al[rt], bh, c[ntl][rt]);
                c[ntl][rt] = MFMA(ah[rt], bl, c[ntl][rt]);
            }
        }
    }
}

__device__ __forceinline__ void gather_f32(
    const unsigned char* H, const int* srt, int st, int en, int cq, float (&acc)[32])
{
    for (int i = st; i < en; ++i) {
        const int s = srt[i];
        const unsigned char* rp = H + s*512;
        const int sw2 = (s & 15) << 4;
        #pragma unroll
        for (int u = 0; u < 8; ++u) {
            f32x4 v = *(const f32x4*)(rp + ((cq*128 + u*16) ^ sw2));
            acc[u*4+0] += v[0]; acc[u*4+1] += v[1];
            acc[u*4+2] += v[2]; acc[u*4+3] += v[3];
        }
    }
}
__device__ __forceinline__ void gather_b16(
    const unsigned char* H, const int* srt, int st, int en, int cq, float (&acc)[32])
{
    for (int i = st; i < en; ++i) {
        const int s = srt[i];
        const unsigned char* rp = H + s*256;
        const int sw2 = (s & 15) << 4;
        #pragma unroll
        for (int u = 0; u < 4; ++u) {
            u16x8 v = *(const u16x8*)(rp + ((cq*64 + u*16) ^ sw2));
            #pragma unroll
            for (int j = 0; j < 8; ++j) acc[u*8+j] += b2f(v[j]);
        }
    }
}
__device__ __forceinline__ void writeA(
    unsigned char* Ah, unsigned char* Al, int d, int cq, const float (&acc)[32])
{
    unsigned char* wh = Ah + d*256;
    unsigned char* wl = Al + d*256;
    const int dw = (d & 15) << 4;
    #pragma unroll
    for (int u = 0; u < 4; ++u) {
        u16x8 oh, ol;
        #pragma unroll
        for (int j = 0; j < 8; ++j) {
            float x = acc[u*8+j];
            u16 h = f2b(x); oh[j] = h; ol[j] = f2b(x - b2f(h));
        }
        *(u16x8*)(wh + ((cq*64 + u*16) ^ dw)) = oh;
        *(u16x8*)(wl + ((cq*64 + u*16) ^ dw)) = ol;
    }
}

// ---------------------------------------------------------------------------
// k_prep: fragment-major hi/lo bf16 weight buffers.
// frag (nt,kb): lane l elem j -> W[k = kb*32 + (l>>4)*8 + j][col = nt*16 + (l&15)]
// ---------------------------------------------------------------------------
__global__ __launch_bounds__(256) void k_prep(
    const float* __restrict__ W_adj, const float* __restrict__ W_occ,
    const float* __restrict__ W_att, const float* __restrict__ W_def,
    const float* __restrict__ W_rev, const float* __restrict__ W_out,
    const float* __restrict__ W_ph, u16* __restrict__ wb)
{
    int gid = blockIdx.x*256 + threadIdx.x;     // 348*256 = 89088 = 1392 frags
    int fid = gid >> 6, lane = gid & 63;
    int g8 = (lane >> 4) * 8, lr = lane & 15;
    const float* src; int ld, f, oh, ol;
    if (fid < 32)       { src = W_adj; ld = HID;  f = fid;      oh = OFF_WADJ_H; ol = OFF_WADJ_L; }
    else if (fid < 64)  { src = W_occ; ld = HID;  f = fid-32;   oh = OFF_WOCC_H; ol = OFF_WOCC_L; }
    else if (fid < 96)  { src = W_att; ld = HID;  f = fid-64;   oh = OFF_WATT_H; ol = OFF_WATT_L; }
    else if (fid < 128) { src = W_def; ld = HID;  f = fid-96;   oh = OFF_WDEF_H; ol = OFF_WDEF_L; }
    else if (fid < 160) { src = W_rev; ld = HID;  f = fid-128;  oh = OFF_WREV_H; ol = OFF_WREV_L; }
    else if (fid < 224) { src = W_out; ld = DOUT; f = fid-160;  oh = OFF_WOUT_H; ol = OFF_WOUT_L; }
    else                { src = W_ph;  ld = ADIM; f = fid-224;  oh = OFF_WPH_H;  ol = OFF_WPH_L; }
    int nt = f >> 2, kb = f & 3;
    int col = nt*16 + lr;
    u16x8 vh, vl;
    #pragma unroll
    for (int j = 0; j < 8; ++j) {
        int k = kb*32 + g8 + j;
        u16 h, l; split2(src[k*ld + col], h, l);
        vh[j] = h; vl[j] = l;
    }
    *(u16x8*)(wb + oh + (f*64 + lane)*8) = vh;
    *(u16x8*)(wb + ol + (f*64 + lane)*8) = vl;
}

// ---------------------------------------------------------------------------
// k_sq: per-batch square pipeline. 256 thr, 2 blocks/CU (75 KB dynamic LDS).
// ---------------------------------------------------------------------------
__global__ __launch_bounds__(256, 2) void k_sq(
    const float* __restrict__ x_sq, const float* __restrict__ x_pc,
    const float* __restrict__ W_in_sq, const float* __restrict__ b_in_sq,
    const float* __restrict__ W_in_pc, const float* __restrict__ b_in_pc,
    const float* __restrict__ b_out,
    const int* __restrict__ ei_adj, const int* __restrict__ ei_occ,
    const u16* __restrict__ wb, float* __restrict__ shared_out)
{
    extern __shared__ __align__(16) unsigned char SMb[];
    unsigned char* Hs = SMb + HS_OFF;
    unsigned char* Ah = SMb + AH_OFF;
    unsigned char* Al = SMb + AL_OFF;
    unsigned char* Hp = SMb + HP_OFF;
    int* e_pk  = (int*)(SMb + EPK_OFF);
    int* srt_a = (int*)(SMb + SRT_OFF);
    int* rs_a  = (int*)(SMb + RSA_OFF);
    int* cur_a = (int*)(SMb + CURA_OFF);
    int* cnt_a = (int*)(SMb + CNTA_OFF);
    int* rs_o  = (int*)(SMb + RSO_OFF);
    int* cur_o = (int*)(SMb + CURO_OFF);
    int* cnt_o = (int*)(SMb + CNTO_OFF);
    int* srt_o = (int*)(SMb + SRTO_OFF);
    int* o_pk  = (int*)(SMb + OPK_OFF);
    float* xs = (float*)Ah;            // [64][16] alias (dead before A written)
    float* xp = (float*)(Ah + 4096);   // [24][16] alias

    const int t = threadIdx.x, b = blockIdx.x;
    const int w = t >> 6, lane = t & 63, g = lane >> 4, lr = lane & 15;

    // ---- ph0: loads ----
    for (int i = t; i < E_ADJ; i += 256) {
        int s = ei_adj[b*E_ADJ + i] - b*SQN;
        int d = ei_adj[E_ADJ_TOT + b*E_ADJ + i] - b*SQN;
        e_pk[i] = s | (d << 16);
    }
    if (t < PCN) {
        int s = ei_occ[b*PCN + t] - b*PCN;
        int d = ei_occ[NPCT + b*PCN + t] - b*SQN;
        o_pk[t] = s | (d << 16);
    }
    if (t < 64) { cnt_a[t] = 0; cnt_o[t] = 0; }
    for (int i = t; i < SQN*FEAT; i += 256) xs[i] = x_sq[b*SQN*FEAT + i];
    for (int i = t; i < PCN*FEAT; i += 256) xp[i] = x_pc[b*PCN*FEAT + i];
    __syncthreads();

    // ---- ph1: count per dst ----
    for (int i = t; i < E_ADJ; i += 256) atomicAdd(&cnt_a[e_pk[i] >> 16], 1);
    if (t < PCN) atomicAdd(&cnt_o[o_pk[t] >> 16], 1);
    __syncthreads();

    // ---- ph2: exclusive scans ----
    if (t < 64) {
        int v = cnt_a[t], o0 = v;
        for (int o = 1; o < 64; o <<= 1) { int u = __shfl_up(v, o); if (t >= o) v += u; }
        rs_a[t+1] = v; cur_a[t] = v - o0; if (t == 0) rs_a[0] = 0;
    } else if (t < 128) {
        int l = t - 64;
        int v = cnt_o[l], o0 = v;
        for (int o = 1; o < 64; o <<= 1) { int u = __shfl_up(v, o); if (l >= o) v += u; }
        rs_o[l+1] = v; cur_o[l] = v - o0; if (l == 0) rs_o[0] = 0;
    }
    __syncthreads();

    // ---- ph3: place sorted src; P1: input GEMMs (fp32) -> Hs (f32 swz), Hp (bf16 swz) ----
    for (int i = t; i < E_ADJ; i += 256) {
        int pk = e_pk[i];
        int p = atomicAdd(&cur_a[pk >> 16], 1);
        srt_a[p] = pk & 0xffff;
    }
    if (t < PCN) {
        int pk = o_pk[t];
        int p = atomicAdd(&cur_o[pk >> 16], 1);
        srt_o[p] = pk & 0xffff;
    }
    {
        const int c = t & 127, r0 = t >> 7;
        float wv[16];
        #pragma unroll
        for (int k = 0; k < 16; ++k) wv[k] = W_in_sq[k*HID + c];
        float bb = b_in_sq[c];
        for (int r = r0; r < SQN; r += 2) {
            float h = gelu_f(bb + dot16(xs + r*FEAT, wv));
            *(float*)(Hs + r*512 + ((c*4) ^ ((r&15)<<4))) = h;
        }
        #pragma unroll
        for (int k = 0; k < 16; ++k) wv[k] = W_in_pc[k*HID + c];
        bb = b_in_pc[c];
        for (int r = r0; r < PCN; r += 2) {
            float h = gelu_f(bb + dot16(xp + r*FEAT, wv));
            *(u16*)(Hp + r*256 + ((c*2) ^ ((r&15)<<4))) = f2b(h);
        }
    }
    __syncthreads();

    // ---- ph4: adj gather (fp32) -> A hi/lo ----
    {
        const int d = t >> 2, cq = t & 3;
        float acc[32];
        #pragma unroll
        for (int i = 0; i < 32; ++i) acc[i] = 0.f;
        gather_f32(Hs, srt_a, rs_a[d], rs_a[d+1], cq, acc);
        writeA(Ah, Al, d, cq, acc);
    }
    __syncthreads();

    // ---- ph5: GEMM1a: c1 += A_adj @ W_adj ----
    f32x4 c1[2][4];
    {
        const f32x4 z = {0.f,0.f,0.f,0.f};
        #pragma unroll
        for (int n = 0; n < 2; ++n)
            #pragma unroll
            for (int rt = 0; rt < 4; ++rt) c1[n][rt] = z;
    }
    gemm_2nt<4>(Ah, Al, wb + OFF_WADJ_H, wb + OFF_WADJ_L, w, lane, g, lr, c1);
    __syncthreads();

    // ---- ph6: occ gather (bf16 hi) -> A hi/lo ----
    {
        const int d = t >> 2, cq = t & 3;
        float acc[32];
        #pragma unroll
        for (int i = 0; i < 32; ++i) acc[i] = 0.f;
        gather_b16(Hp, srt_o, rs_o[d], rs_o[d+1], cq, acc);
        writeA(Ah, Al, d, cq, acc);
    }
    __syncthreads();

    // ---- ph7: GEMM1b: c1 += A_occ @ W_occ ----
    gemm_2nt<4>(Ah, Al, wb + OFF_WOCC_H, wb + OFF_WOCC_L, w, lane, g, lr, c1);
    __syncthreads();

    // ---- ph8: epi1: h2 = gelu(h + agg) -> A hi/lo ----
    #pragma unroll
    for (int ntl = 0; ntl < 2; ++ntl) {
        const int col = (w*2 + ntl)*16 + lr;
        #pragma unroll
        for (int rt = 0; rt < 4; ++rt)
            #pragma unroll
            for (int r = 0; r < 4; ++r) {
                const int row = rt*16 + g*4 + r;
                float hv = *(const float*)(Hs + row*512 + ((col*4) ^ ((row&15)<<4)));
                float h2 = gelu_f(c1[ntl][rt][r] + hv);
                u16 hh, ll; split2(h2, hh, ll);
                const int bo = row*256 + ((col*2) ^ ((row&15)<<4));
                *(u16*)(Ah + bo) = hh;
                *(u16*)(Al + bo) = ll;
            }
    }
    __syncthreads();

    // ---- ph9: GEMM2 (W_out) + epilogue colsum/64 ----
    f32x4 c2[4][4];
    {
        const f32x4 z = {0.f,0.f,0.f,0.f};
        #pragma unroll
        for (int n = 0; n < 4; ++n)
            #pragma unroll
            for (int rt = 0; rt < 4; ++rt) c2[n][rt] = z;
    }
    gemm_4nt<4>(Ah, Al, wb + OFF_WOUT_H, wb + OFF_WOUT_L, w, lane, g, lr, c2);
    #pragma unroll
    for (int ntl = 0; ntl < 4; ++ntl) {
        const int col = (w*4 + ntl)*16 + lr;
        const float bias = b_out[col];
        float cs = 0.f;
        #pragma unroll
        for (int rt = 0; rt < 4; ++rt)
            #pragma unroll
            for (int r = 0; r < 4; ++r) cs += gelu_f(c2[ntl][rt][r] + bias);
        cs += __shfl_xor(cs, 16);
        cs += __shfl_xor(cs, 32);
        if (lane < 16) shared_out[b*DOUT + col] = cs * (1.0f/64.0f);
    }
}

// ---------------------------------------------------------------------------
// k_pc: 2 batches/block piece pipeline. 256 thr, 3 blocks/CU (51 KB LDS).
// ---------------------------------------------------------------------------
#define PHP_OFF  0        // [48][512B] fp32 swizzled
#define PAH_OFF  24576    // [48][256B]
#define PAL_OFF  36864    // [48][256B]
#define PEA_OFF  49152    // 80 packed att
#define PED_OFF  49472    // 80 packed def
#define PSA_OFF  49792    // 80
#define PSD_OFF  50112    // 80
#define PRSA_OFF 50432    // 65
#define PCUA_OFF 50692    // 64
#define PCNA_OFF 50948    // 64
#define PRSD_OFF 51204    // 65
#define PCUD_OFF 51464    // 64
#define PCND_OFF 51720    // 64
#define PRVS_OFF 51976    // 48
#define PRVD_OFF 52168    // 48
#define KPC_SMEM 52360

__global__ __launch_bounds__(256, 3) void k_pc(
    const float* __restrict__ x_sq, const float* __restrict__ x_pc,
    const float* __restrict__ W_in_sq, const float* __restrict__ b_in_sq,
    const float* __restrict__ W_in_pc, const float* __restrict__ b_in_pc,
    const float* __restrict__ b_out,
    const int* __restrict__ ei_att, const int* __restrict__ ei_def,
    const int* __restrict__ ei_rev,
    const u16* __restrict__ wb, float* __restrict__ shared_out)
{
    __shared__ __align__(16) unsigned char SMb[KPC_SMEM];
    unsigned char* Hp = SMb + PHP_OFF;
    unsigned char* Ah = SMb + PAH_OFF;
    unsigned char* Al = SMb + PAL_OFF;
    int* ea_pk = (int*)(SMb + PEA_OFF);
    int* ed_pk = (int*)(SMb + PED_OFF);
    int* srt_a = (int*)(SMb + PSA_OFF);
    int* srt_d = (int*)(SMb + PSD_OFF);
    int* rs_a  = (int*)(SMb + PRSA_OFF);
    int* cur_a = (int*)(SMb + PCUA_OFF);
    int* cnt_a = (int*)(SMb + PCNA_OFF);
    int* rs_d  = (int*)(SMb + PRSD_OFF);
    int* cur_d = (int*)(SMb + PCUD_OFF);
    int* cnt_d = (int*)(SMb + PCND_OFF);
    int* rv_s  = (int*)(SMb + PRVS_OFF);
    int* rv_d  = (int*)(SMb + PRVD_OFF);
    float* xp = (float*)Ah;            // [48][16] alias
    float* xg = (float*)(Ah + 3072);   // [48][16] alias

    const int t = threadIdx.x;
    const int w = t >> 6, lane = t & 63, g = lane >> 4, lr = lane & 15;
    const int NR = 2*PCN;   // 48

    // ---- ph0 ----
    for (int i = t; i < 2*E_ATT; i += 256) {
        int sb = (i >= E_ATT) ? 1 : 0;
        int e = i - sb*E_ATT;
        int gb = blockIdx.x*2 + sb;
        int ro = sb*PCN - gb*PCN;
        int s = ei_att[gb*E_ATT + e] + ro;
        int d = ei_att[E_ATT_TOT + gb*E_ATT + e] + ro;
        ea_pk[i] = s | (d << 16);
        s = ei_def[gb*E_ATT + e] + ro;
        d = ei_def[E_ATT_TOT + gb*E_ATT + e] + ro;
        ed_pk[i] = s | (d << 16);
    }
    if (t < NR) {
        int sb = (t >= PCN) ? 1 : 0;
        int gb = blockIdx.x*2 + sb;
        int p = t - sb*PCN;
        rv_s[t] = ei_rev[gb*PCN + p];
        rv_d[t] = ei_rev[NPCT + gb*PCN + p] - gb*PCN + sb*PCN;
    }
    if (t < 64) { cnt_a[t] = 0; cnt_d[t] = 0; }
    for (int i = t; i < NR*FEAT; i += 256) xp[i] = x_pc[blockIdx.x*2*PCN*FEAT + i];
    __syncthreads();

    // ---- ph1: counts + xg gather ----
    for (int i = t; i < 2*E_ATT; i += 256) {
        atomicAdd(&cnt_a[ea_pk[i] >> 16], 1);
        atomicAdd(&cnt_d[ed_pk[i] >> 16], 1);
    }
    for (int i = t; i < NR*FEAT; i += 256) xg[i] = x_sq[rv_s[i >> 4]*FEAT + (i & 15)];
    __syncthreads();

    // ---- ph2: scans ----
    if (t < 64) {
        int v = cnt_a[t], o0 = v;
        for (int o = 1; o < 64; o <<= 1) { int u = __shfl_up(v, o); if (t >= o) v += u; }
        rs_a[t+1] = v; cur_a[t] = v - o0; if (t == 0) rs_a[0] = 0;
    } else if (t < 128) {
        int l = t - 64;
        int v = cnt_d[l], o0 = v;
        for (int o = 1; o < 64; o <<= 1) { int u = __shfl_up(v, o); if (l >= o) v += u; }
        rs_d[l+1] = v; cur_d[l] = v - o0; if (l == 0) rs_d[0] = 0;
    }
    __syncthreads();

    // ---- ph3: place; hp = gelu(xp@W_in_pc+b) fp32; rev-h into regs ----
    for (int i = t; i < 2*E_ATT; i += 256) {
        int pk = ea_pk[i];
        int p = atomicAdd(&cur_a[pk >> 16], 1); srt_a[p] = pk & 0xffff;
        pk = ed_pk[i];
        p = atomicAdd(&cur_d[pk >> 16], 1); srt_d[p] = pk & 0xffff;
    }
    float hrev[24];
    {
        const int c = t & 127, r0 = t >> 7;
        float wv[16];
        #pragma unroll
        for (int k = 0; k < 16; ++k) wv[k] = W_in_pc[k*HID + c];
        float bb = b_in_pc[c];
        for (int r = r0; r < NR; r += 2) {
            float h = gelu_f(bb + dot16(xp + r*FEAT, wv));
            *(float*)(Hp + r*512 + ((c*4) ^ ((r&15)<<4))) = h;
        }
        #pragma unroll
        for (int k = 0; k < 16; ++k) wv[k] = W_in_sq[k*HID + c];
        bb = b_in_sq[c];
        #pragma unroll
        for (int idx = 0; idx < 24; ++idx) {
            int r = r0 + 2*idx;
            hrev[idx] = gelu_f(bb + dot16(xg + r*FEAT, wv));
        }
    }
    __syncthreads();   // xg reads done

    // ---- ph4: write rev rows -> A hi/lo (rv_d is a permutation) ----
    {
        const int c = t & 127, r0 = t >> 7;
        #pragma unroll
        for (int idx = 0; idx < 24; ++idx) {
            int r = r0 + 2*idx;
            int dr = rv_d[r];
            u16 hh, ll; split2(hrev[idx], hh, ll);
            const int bo = dr*256 + ((c*2) ^ ((dr&15)<<4));
            *(u16*)(Ah + bo) = hh;
            *(u16*)(Al + bo) = ll;
        }
    }
    __syncthreads();

    // ---- ph5: GEMM1c: c1 += A_rev @ W_rev ----
    f32x4 c1[2][3];
    {
        const f32x4 z = {0.f,0.f,0.f,0.f};
        #pragma unroll
        for (int n = 0; n < 2; ++n)
            #pragma unroll
            for (int rt = 0; rt < 3; ++rt) c1[n][rt] = z;
    }
    gemm_2nt<3>(Ah, Al, wb + OFF_WREV_H, wb + OFF_WREV_L, w, lane, g, lr, c1);
    __syncthreads();

    // ---- ph6: att gather -> A ----
    {
        const int d = t >> 2, cq = t & 3;
        if (d < NR) {
            float acc[32];
            #pragma unroll
            for (int i = 0; i < 32; ++i) acc[i] = 0.f;
            gather_f32(Hp, srt_a, rs_a[d], rs_a[d+1], cq, acc);
            writeA(Ah, Al, d, cq, acc);
        }
    }
    __syncthreads();

    // ---- ph7: GEMM1a (W_att) ----
    gemm_2nt<3>(Ah, Al, wb + OFF_WATT_H, wb + OFF_WATT_L, w, lane, g, lr, c1);
    __syncthreads();

    // ---- ph8: def gather -> A ----
    {
        const int d = t >> 2, cq = t & 3;
        if (d < NR) {
            float acc[32];
            #pragma unroll
            for (int i = 0; i < 32; ++i) acc[i] = 0.f;
            gather_f32(Hp, srt_d, rs_d[d], rs_d[d+1], cq, acc);
            writeA(Ah, Al, d, cq, acc);
        }
    }
    __syncthreads();

    // ---- ph9: GEMM1b (W_def) ----
    gemm_2nt<3>(Ah, Al, wb + OFF_WDEF_H, wb + OFF_WDEF_L, w, lane, g, lr, c1);
    __syncthreads();

    // ---- ph10: epi1: h2 = gelu(hp + agg) -> A ----
    #pragma unroll
    for (int ntl = 0; ntl < 2; ++ntl) {
        const int col = (w*2 + ntl)*16 + lr;
        #pragma unroll
        for (int rt = 0; rt < 3; ++rt)
            #pragma unroll
            for (int r = 0; r < 4; ++r) {
                const int row = rt*16 + g*4 + r;
                float hv = *(const float*)(Hp + row*512 + ((col*4) ^ ((row&15)<<4)));
                float h2 = gelu_f(c1[ntl][rt][r] + hv);
                u16 hh, ll; split2(h2, hh, ll);
                const int bo = row*256 + ((col*2) ^ ((row&15)<<4));
                *(u16*)(Ah + bo) = hh;
                *(u16*)(Al + bo) = ll;
            }
    }
    __syncthreads();

    // ---- ph11: GEMM2 (W_out) + per-sub-batch colsum/24 ----
    f32x4 c2[4][3];
    {
        const f32x4 z = {0.f,0.f,0.f,0.f};
        #pragma unroll
        for (int n = 0; n < 4; ++n)
            #pragma unroll
            for (int rt = 0; rt < 3; ++rt) c2[n][rt] = z;
    }
    gemm_4nt<3>(Ah, Al, wb + OFF_WOUT_H, wb + OFF_WOUT_L, w, lane, g, lr, c2);
    #pragma unroll
    for (int ntl = 0; ntl < 4; ++ntl) {
        const int col = (w*4 + ntl)*16 + lr;
        const float bias = b_out[col];
        float s0 = 0.f, s1 = 0.f;
        #pragma unroll
        for (int r = 0; r < 4; ++r) s0 += gelu_f(c2[ntl][0][r] + bias);
        {
            float tt = 0.f;
            #pragma unroll
            for (int r = 0; r < 4; ++r) tt += gelu_f(c2[ntl][1][r] + bias);
            s0 += (g < 2) ? tt : 0.f;
            s1 += (g < 2) ? 0.f : tt;
        }
        #pragma unroll
        for (int r = 0; r < 4; ++r) s1 += gelu_f(c2[ntl][2][r] + bias);
        s0 += __shfl_xor(s0, 16); s0 += __shfl_xor(s0, 32);
        s1 += __shfl_xor(s1, 16); s1 += __shfl_xor(s1, 32);
        if (lane < 16) {
            const int b0 = blockIdx.x*2, b1 = b0 + 1;
            shared_out[b0*DOUT + col] += s0 * (1.0f/PCN);
            shared_out[b1*DOUT + col] += s1 * (1.0f/PCN);
        }
    }
}

// ---------------------------------------------------------------------------
// k_head: tpol(hi/lo bf16) = gelu(shared@W_pt+b); value head fp32
// ---------------------------------------------------------------------------
__global__ __launch_bounds__(256) void k_head(
    const float* __restrict__ shared_in,
    const float* __restrict__ W_pt, const float* __restrict__ b_pt,
    const float* __restrict__ W_vt, const float* __restrict__ b_vt,
    const float* __restrict__ W_vh, const float* __restrict__ b_vh,
    u16* __restrict__ tpol_h, u16* __restrict__ tpol_l, float* __restrict__ out_value)
{
    __shared__ float sh[2*DOUT];
    __shared__ float vred[2*TDIM];
    const int t = threadIdx.x;
    const int hh = t >> 7, j = t & 127;
    const int b = blockIdx.x*2 + hh;
    for (int i = t; i < 2*DOUT; i += 256) sh[i] = shared_in[blockIdx.x*2*DOUT + i];
    __syncthreads();
    const float* s = sh + hh*DOUT;
    float ap = b_pt[j], av = b_vt[j];
    #pragma unroll 8
    for (int k = 0; k < DOUT; ++k) {
        float sv = s[k];
        ap += sv * W_pt[k*TDIM + j];
        av += sv * W_vt[k*TDIM + j];
    }
    float tv = gelu_f(ap);
    u16 th, tl; split2(tv, th, tl);
    tpol_h[b*TDIM + j] = th;
    tpol_l[b*TDIM + j] = tl;
    vred[hh*TDIM + j] = gelu_f(av) * W_vh[j];
    __syncthreads();
    for (int stp = 64; stp > 0; stp >>= 1) {
        if (j < stp) vred[hh*TDIM + j] += vred[hh*TDIM + j + stp];
        __syncthreads();
    }
    if (j == 0) out_value[b] = tanhf(vred[hh*TDIM] + b_vh[0]);
}

// ---------------------------------------------------------------------------
// k_pol: policy = tpol @ W_ph + b_ph, split-bf16 MFMA. grid (73, 32).
// ---------------------------------------------------------------------------
__global__ __launch_bounds__(256) void k_pol(
    const u16* __restrict__ tpol_h, const u16* __restrict__ tpol_l,
    const u16* __restrict__ wb, const float* __restrict__ b_ph,
    float* __restrict__ pol)
{
    const u16* wph_h = wb + OFF_WPH_H;
    const u16* wph_l = wb + OFF_WPH_L;
    const int t = threadIdx.x, w = t >> 6, lane = t & 63, g = lane >> 4, lr = lane & 15;
    const int nt = blockIdx.x*4 + w;       // 0..291
    const int rbase = blockIdx.y*64;
    f32x4 acc[4];
    const f32x4 z = {0.f,0.f,0.f,0.f};
    #pragma unroll
    for (int rt = 0; rt < 4; ++rt) acc[rt] = z;
    #pragma unroll
    for (int ks = 0; ks < 4; ++ks) {
        bf16x8 bh = *(const bf16x8*)(wph_h + ((nt*4 + ks)*64 + lane)*8);
        bf16x8 bl = *(const bf16x8*)(wph_l + ((nt*4 + ks)*64 + lane)*8);
        #pragma unroll
        for (int rt = 0; rt < 4; ++rt) {
            const int ro = (rbase + rt*16 + lr)*TDIM + ks*32 + g*8;
            bf16x8 ah = *(const bf16x8*)(tpol_h + ro);
            bf16x8 al = *(const bf16x8*)(tpol_l + ro);
            acc[rt] = MFMA(ah, bh, acc[rt]);
            acc[rt] = MFMA(al, bh, acc[rt]);
            acc[rt] = MFMA(ah, bl, acc[rt]);
        }
    }
    const float bias = b_ph[nt*16 + lr];
    #pragma unroll
    for (int rt = 0; rt < 4; ++rt)
        #pragma unroll
        for (int r = 0; r < 4; ++r) {
            int row = rbase + rt*16 + g*4 + r;
            pol[(size_t)row*ADIM + nt*16 + lr] = acc[rt][r] + bias;
        }
}

// ---------------------------------------------------------------------------
extern "C" void kernel_launch(void* const* d_in, const int* in_sizes, int n_in,
                              void* d_out, int out_size, void* d_ws, size_t ws_size,
                              hipStream_t stream) {
    (void)in_sizes; (void)n_in; (void)out_size; (void)ws_size;
    const float* x_sq    = (const float*)d_in[0];
    const float* x_pc    = (const float*)d_in[1];
    const float* W_in_sq = (const float*)d_in[2];
    const float* b_in_sq = (const float*)d_in[3];
    const float* W_in_pc = (const float*)d_in[4];
    const float* b_in_pc = (const float*)d_in[5];
    const float* W_adj   = (const float*)d_in[6];
    const float* W_occ   = (const float*)d_in[7];
    const float* W_att   = (const float*)d_in[8];
    const float* W_def   = (const float*)d_in[9];
    const float* W_rev   = (const float*)d_in[10];
    const float* W_out   = (const float*)d_in[11];
    const float* b_out   = (const float*)d_in[12];
    const float* W_pt    = (const float*)d_in[13];
    const float* b_pt    = (const float*)d_in[14];
    const float* W_vt    = (const float*)d_in[15];
    const float* b_vt    = (const float*)d_in[16];
    const float* W_ph    = (const float*)d_in[17];
    const float* b_ph    = (const float*)d_in[18];
    const float* W_vh    = (const float*)d_in[19];
    const float* b_vh    = (const float*)d_in[20];
    const int* ei_adj    = (const int*)d_in[21];
    const int* ei_occ    = (const int*)d_in[22];
    const int* ei_att    = (const int*)d_in[23];
    const int* ei_def    = (const int*)d_in[24];
    const int* ei_rev    = (const int*)d_in[25];

    float* out = (float*)d_out;
    float* pol = out;
    float* val = out + (size_t)BATCH * ADIM;

    float* shared_buf = (float*)d_ws;                    // [2048][256] f32
    u16* tpol_h = (u16*)(shared_buf + BATCH*DOUT);       // [2048][128] bf16
    u16* tpol_l = tpol_h + BATCH*TDIM;
    u16* wb     = tpol_l + BATCH*TDIM;                   // 1425408 u16 frag buffer

    hipFuncSetAttribute((const void*)k_sq,
                        hipFuncAttributeMaxDynamicSharedMemorySize, KSQ_SMEM);

    k_prep<<<348, 256, 0, stream>>>(W_adj, W_occ, W_att, W_def, W_rev, W_out, W_ph, wb);
    k_sq<<<BATCH, 256, KSQ_SMEM, stream>>>(x_sq, x_pc, W_in_sq, b_in_sq, W_in_pc, b_in_pc,
                                           b_out, ei_adj, ei_occ, wb, shared_buf);
    k_pc<<<BATCH/2, 256, 0, stream>>>(x_sq, x_pc, W_in_sq, b_in_sq, W_in_pc, b_in_pc,
                                      b_out, ei_att, ei_def, ei_rev, wb, shared_buf);
    k_head<<<BATCH/2, 256, 0, stream>>>(shared_buf, W_pt, b_pt, W_vt, b_vt, W_vh, b_vh,
                                        tpol_h, tpol_l, val);
    k_pol<<<dim3(ADIM/64, BATCH/64), 256, 0, stream>>>(tpol_h, tpol_l, wb, b_ph, pol);
}

// Round 5
// 226.812 us; speedup vs baseline: 4.8724x; 1.1631x over previous
//
#include <hip/hip_runtime.h>

#define BATCH 2048
#define SQN 64
#define PCN 24
#define FEAT 16
#define HID 128
#define DOUT 256
#define TDIM 128
#define ADIM 4672
#define NSQT (BATCH*SQN)
#define NPCT (BATCH*PCN)
#define E_ADJ 420
#define E_ATT 40
#define E_ADJ_TOT (BATCH*E_ADJ)
#define E_ATT_TOT (BATCH*E_ATT)

typedef unsigned short u16;
typedef unsigned int u32;
typedef __attribute__((ext_vector_type(8))) short bf16x8;
typedef __attribute__((ext_vector_type(8))) unsigned short u16x8;
typedef __attribute__((ext_vector_type(4))) float f32x4;

// ---- weight fragment buffer offsets (u16 units), hi/lo split ----
#define OFF_WADJ_H 0
#define OFF_WADJ_L 16384
#define OFF_WOCC_H 32768
#define OFF_WOCC_L 49152
#define OFF_WATT_H 65536
#define OFF_WATT_L 81920
#define OFF_WDEF_H 98304
#define OFF_WDEF_L 114688
#define OFF_WREV_H 131072
#define OFF_WREV_L 147456
#define OFF_WOUT_H 163840
#define OFF_WOUT_L 196608
#define OFF_WPH_H  229376
#define OFF_WPH_L  827392
#define OFF_WINSQ_H 1425408
#define OFF_WINSQ_L 1429504
#define OFF_WINPC_H 1433600
#define OFF_WINPC_L 1437696
#define WB_TOTAL    1441792

// ---- k_sq dynamic LDS layout (bytes) ----
#define HS_OFF   0        // [64][512B] fp32 swizzled
#define AH_OFF   32768    // [64][256B] bf16 swizzled
#define AL_OFF   49152    // [64][256B] bf16 swizzled
#define HP_OFF   65536    // [24][256B] bf16 swizzled (hi only; occ path)
#define EPK_OFF  71680    // 420 packed (src | dst<<16)
#define SRT_OFF  73360    // 420
#define RSA_OFF  75040    // 65
#define CURA_OFF 75300    // 64
#define CNTA_OFF 75556    // 64
#define RSO_OFF  75812    // 65
#define CURO_OFF 76072    // 64
#define CNTO_OFF 76328    // 64
#define SRTO_OFF 76584    // 24
#define OPK_OFF  76680    // 24
#define KSQ_SMEM 76776

// ---- k_pc LDS layout (within same dynamic buffer) ----
#define PHP_OFF  0        // [48][512B] fp32 swizzled
#define PAH_OFF  24576    // [48][256B]
#define PAL_OFF  36864    // [48][256B]
#define PEA_OFF  49152    // 80 packed att
#define PED_OFF  49472    // 80 packed def
#define PSA_OFF  49792    // 80
#define PSD_OFF  50112    // 80
#define PRSA_OFF 50432    // 65
#define PCUA_OFF 50692    // 64
#define PCNA_OFF 50948    // 64
#define PRSD_OFF 51204    // 65
#define PCUD_OFF 51464    // 64
#define PCND_OFF 51720    // 64
#define PRVS_OFF 51976    // 48
#define PRVD_OFF 52168    // 48

__device__ __forceinline__ float gelu_f(float x) {
    float z = 0.7978845608028654f * (x + 0.044715f * x * x * x);
    float e = __expf(2.0f * z);
    float t = 1.0f - 2.0f / (e + 1.0f);
    return 0.5f * x * (1.0f + t);
}
__device__ __forceinline__ u16 f2b(float x) {   // fp32 -> bf16 RNE
    u32 u = __float_as_uint(x);
    u += 0x7fffu + ((u >> 16) & 1u);
    return (u16)(u >> 16);
}
__device__ __forceinline__ float b2f(u16 h) { return __uint_as_float(((u32)h) << 16); }
__device__ __forceinline__ void split2(float x, u16& h, u16& l) {
    u16 hh = f2b(x); h = hh; l = f2b(x - b2f(hh));
}
__device__ __forceinline__ f32x4 MFMA(bf16x8 a, bf16x8 b, f32x4 c) {
    return __builtin_amdgcn_mfma_f32_16x16x32_bf16(a, b, c, 0, 0, 0);
}
__device__ __forceinline__ bf16x8 bzero() {
    bf16x8 v = {0,0,0,0,0,0,0,0}; return v;
}
// build hi/lo A-frag from a 16-float global row (g<2 callers only)
__device__ __forceinline__ void xfrag(const float* __restrict__ xrow, int g,
                                      bf16x8& ah, bf16x8& al)
{
    f32x4 a = *(const f32x4*)(xrow + g*8);
    f32x4 b = *(const f32x4*)(xrow + g*8 + 4);
    #pragma unroll
    for (int j = 0; j < 4; ++j) {
        u16 h, l;
        split2(a[j], h, l); ah[j]   = (short)h; al[j]   = (short)l;
        split2(b[j], h, l); ah[4+j] = (short)h; al[4+j] = (short)l;
    }
}

// GEMM over K=128, NT n-tiles per wave starting ntBase, split-bf16 3-term.
template<int NT, int RT>
__device__ __forceinline__ void gemm_nt(
    const unsigned char* Ah, const unsigned char* Al,
    const u16* __restrict__ wh, const u16* __restrict__ wl,
    int ntBase, int lane, int g, int lr, f32x4 (&c)[NT][RT])
{
    const int sw = lr << 4;
    #pragma unroll
    for (int ks = 0; ks < 4; ++ks) {
        const int ko = ks*64 + g*16;
        bf16x8 ah[RT], al[RT];
        #pragma unroll
        for (int rt = 0; rt < RT; ++rt) {
            const int ro = (rt*16 + lr)*256 + (ko ^ sw);
            ah[rt] = *(const bf16x8*)(Ah + ro);
            al[rt] = *(const bf16x8*)(Al + ro);
        }
        #pragma unroll
        for (int ntl = 0; ntl < NT; ++ntl) {
            bf16x8 bh = *(const bf16x8*)(wh + (((ntBase+ntl)*4 + ks)*64 + lane)*8);
            bf16x8 bl = *(const bf16x8*)(wl + (((ntBase+ntl)*4 + ks)*64 + lane)*8);
            #pragma unroll
            for (int rt = 0; rt < RT; ++rt) {
                c[ntl][rt] = MFMA(ah[rt], bh, c[ntl][rt]);
                c[ntl][rt] = MFMA(al[rt], bh, c[ntl][rt]);
                c[ntl][rt] = MFMA(ah[rt], bl, c[ntl][rt]);
            }
        }
    }
}

// 512-thread gathers: thread owns (dst row d, 1/8 of the 128-col row)
__device__ __forceinline__ void gather_f32_8(
    const unsigned char* H, const int* srt, int st, int en, int cq8, float (&acc)[16])
{
    for (int i = st; i < en; ++i) {
        const int s = srt[i];
        const unsigned char* rp = H + s*512;
        const int sw2 = (s & 15) << 4;
        #pragma unroll
        for (int u = 0; u < 4; ++u) {
            f32x4 v = *(const f32x4*)(rp + ((cq8*64 + u*16) ^ sw2));
            acc[u*4+0] += v[0]; acc[u*4+1] += v[1];
            acc[u*4+2] += v[2]; acc[u*4+3] += v[3];
        }
    }
}
__device__ __forceinline__ void gather_b16_8(
    const unsigned char* H, const int* srt, int st, int en, int cq8, float (&acc)[16])
{
    for (int i = st; i < en; ++i) {
        const int s = srt[i];
        const unsigned char* rp = H + s*256;
        const int sw2 = (s & 15) << 4;
        #pragma unroll
        for (int u = 0; u < 2; ++u) {
            u16x8 v = *(const u16x8*)(rp + ((cq8*32 + u*16) ^ sw2));
            #pragma unroll
            for (int j = 0; j < 8; ++j) acc[u*8+j] += b2f(v[j]);
        }
    }
}
__device__ __forceinline__ void writeA_8(
    unsigned char* Ah, unsigned char* Al, int d, int cq8, const float (&acc)[16])
{
    unsigned char* wh = Ah + d*256;
    unsigned char* wl = Al + d*256;
    const int dw = (d & 15) << 4;
    #pragma unroll
    for (int u = 0; u < 2; ++u) {
        u16x8 oh, ol;
        #pragma unroll
        for (int j = 0; j < 8; ++j) {
            float x = acc[u*8+j];
            u16 h = f2b(x); oh[j] = h; ol[j] = f2b(x - b2f(h));
        }
        *(u16x8*)(wh + ((cq8*32 + u*16) ^ dw)) = oh;
        *(u16x8*)(wl + ((cq8*32 + u*16) ^ dw)) = ol;
    }
}

// ---------------------------------------------------------------------------
// k_prep: fragment-major hi/lo bf16 weight buffers (now incl. W_in_sq/pc).
// ---------------------------------------------------------------------------
__global__ __launch_bounds__(256) void k_prep(
    const float* __restrict__ W_adj, const float* __restrict__ W_occ,
    const float* __restrict__ W_att, const float* __restrict__ W_def,
    const float* __restrict__ W_rev, const float* __restrict__ W_out,
    const float* __restrict__ W_ph,
    const float* __restrict__ W_in_sq, const float* __restrict__ W_in_pc,
    u16* __restrict__ wb)
{
    int gid = blockIdx.x*256 + threadIdx.x;     // 352*256 -> 1408 frags
    int fid = gid >> 6, lane = gid & 63;
    int g8 = (lane >> 4) * 8, lr = lane & 15;
    u16x8 vh, vl;
    if (fid >= 1392) {   // W_in_sq / W_in_pc: K=16 padded to 32
        int f = fid - 1392;
        const float* src = (f < 8) ? W_in_sq : W_in_pc;
        int oh = (f < 8) ? OFF_WINSQ_H : OFF_WINPC_H;
        int ol = (f < 8) ? OFF_WINSQ_L : OFF_WINPC_L;
        int nt = f & 7;
        int col = nt*16 + lr;
        #pragma unroll
        for (int j = 0; j < 8; ++j) {
            int k = g8 + j;
            float v = (k < 16) ? src[k*HID + col] : 0.f;
            u16 h, l; split2(v, h, l);
            vh[j] = h; vl[j] = l;
        }
        *(u16x8*)(wb + oh + (nt*64 + lane)*8) = vh;
        *(u16x8*)(wb + ol + (nt*64 + lane)*8) = vl;
        return;
    }
    const float* src; int ld, f, oh, ol;
    if (fid < 32)       { src = W_adj; ld = HID;  f = fid;      oh = OFF_WADJ_H; ol = OFF_WADJ_L; }
    else if (fid < 64)  { src = W_occ; ld = HID;  f = fid-32;   oh = OFF_WOCC_H; ol = OFF_WOCC_L; }
    else if (fid < 96)  { src = W_att; ld = HID;  f = fid-64;   oh = OFF_WATT_H; ol = OFF_WATT_L; }
    else if (fid < 128) { src = W_def; ld = HID;  f = fid-96;   oh = OFF_WDEF_H; ol = OFF_WDEF_L; }
    else if (fid < 160) { src = W_rev; ld = HID;  f = fid-128;  oh = OFF_WREV_H; ol = OFF_WREV_L; }
    else if (fid < 224) { src = W_out; ld = DOUT; f = fid-160;  oh = OFF_WOUT_H; ol = OFF_WOUT_L; }
    else                { src = W_ph;  ld = ADIM; f = fid-224;  oh = OFF_WPH_H;  ol = OFF_WPH_L; }
    int nt = f >> 2, kb = f & 3;
    int col = nt*16 + lr;
    #pragma unroll
    for (int j = 0; j < 8; ++j) {
        int k = kb*32 + g8 + j;
        u16 h, l; split2(src[k*ld + col], h, l);
        vh[j] = h; vl[j] = l;
    }
    *(u16x8*)(wb + oh + (f*64 + lane)*8) = vh;
    *(u16x8*)(wb + ol + (f*64 + lane)*8) = vl;
}

// ---------------------------------------------------------------------------
// square-path device function (512 threads, per-batch)
// ---------------------------------------------------------------------------
__device__ __forceinline__ void sq_path(
    unsigned char* SMb, int b, int t,
    const float* __restrict__ x_sq, const float* __restrict__ x_pc,
    const float* __restrict__ b_in_sq, const float* __restrict__ b_in_pc,
    const float* __restrict__ b_out,
    const int* __restrict__ ei_adj, const int* __restrict__ ei_occ,
    const u16* __restrict__ wb, float* __restrict__ shared_sq)
{
    unsigned char* Hs = SMb + HS_OFF;
    unsigned char* Ah = SMb + AH_OFF;
    unsigned char* Al = SMb + AL_OFF;
    unsigned char* Hp = SMb + HP_OFF;
    int* e_pk  = (int*)(SMb + EPK_OFF);
    int* srt_a = (int*)(SMb + SRT_OFF);
    int* rs_a  = (int*)(SMb + RSA_OFF);
    int* cur_a = (int*)(SMb + CURA_OFF);
    int* cnt_a = (int*)(SMb + CNTA_OFF);
    int* rs_o  = (int*)(SMb + RSO_OFF);
    int* cur_o = (int*)(SMb + CURO_OFF);
    int* cnt_o = (int*)(SMb + CNTO_OFF);
    int* srt_o = (int*)(SMb + SRTO_OFF);
    int* o_pk  = (int*)(SMb + OPK_OFF);

    const int w = t >> 6, lane = t & 63, g = lane >> 4, lr = lane & 15;

    // ---- ph0: edge loads ----
    for (int i = t; i < E_ADJ; i += 512) {
        int s = ei_adj[b*E_ADJ + i] - b*SQN;
        int d = ei_adj[E_ADJ_TOT + b*E_ADJ + i] - b*SQN;
        e_pk[i] = s | (d << 16);
    }
    if (t < PCN) {
        int s = ei_occ[b*PCN + t] - b*PCN;
        int d = ei_occ[NPCT + b*PCN + t] - b*SQN;
        o_pk[t] = s | (d << 16);
    }
    if (t < 64) { cnt_a[t] = 0; cnt_o[t] = 0; }
    __syncthreads();

    // ---- ph1: count per dst ----
    for (int i = t; i < E_ADJ; i += 512) atomicAdd(&cnt_a[e_pk[i] >> 16], 1);
    if (t < PCN) atomicAdd(&cnt_o[o_pk[t] >> 16], 1);
    __syncthreads();

    // ---- ph2: exclusive scans ----
    if (t < 64) {
        int v = cnt_a[t], o0 = v;
        for (int o = 1; o < 64; o <<= 1) { int u = __shfl_up(v, o); if (t >= o) v += u; }
        rs_a[t+1] = v; cur_a[t] = v - o0; if (t == 0) rs_a[0] = 0;
    } else if (t < 128) {
        int l = t - 64;
        int v = cnt_o[l], o0 = v;
        for (int o = 1; o < 64; o <<= 1) { int u = __shfl_up(v, o); if (l >= o) v += u; }
        rs_o[l+1] = v; cur_o[l] = v - o0; if (l == 0) rs_o[0] = 0;
    }
    __syncthreads();

    // ---- ph3: place sorted src + MFMA input-GEMMs (x direct from global) ----
    for (int i = t; i < E_ADJ; i += 512) {
        int pk = e_pk[i];
        int p = atomicAdd(&cur_a[pk >> 16], 1);
        srt_a[p] = pk & 0xffff;
    }
    if (t < PCN) {
        int pk = o_pk[t];
        int p = atomicAdd(&cur_o[pk >> 16], 1);
        srt_o[p] = pk & 0xffff;
    }
    {
        const int colp = w*16 + lr;
        // h_sq = gelu(x_sq @ W_in_sq + b): wave w -> ntile w
        f32x4 ch[4];
        const f32x4 z = {0.f,0.f,0.f,0.f};
        #pragma unroll
        for (int rt = 0; rt < 4; ++rt) ch[rt] = z;
        {
            bf16x8 bh = *(const bf16x8*)(wb + OFF_WINSQ_H + (w*64 + lane)*8);
            bf16x8 bl = *(const bf16x8*)(wb + OFF_WINSQ_L + (w*64 + lane)*8);
            #pragma unroll
            for (int rt = 0; rt < 4; ++rt) {
                bf16x8 ah = bzero(), al = bzero();
                if (g < 2) xfrag(x_sq + (b*SQN + rt*16 + lr)*FEAT, g, ah, al);
                ch[rt] = MFMA(ah, bh, ch[rt]);
                ch[rt] = MFMA(al, bh, ch[rt]);
                ch[rt] = MFMA(ah, bl, ch[rt]);
            }
        }
        const float bbs = b_in_sq[colp];
        #pragma unroll
        for (int rt = 0; rt < 4; ++rt)
            #pragma unroll
            for (int r = 0; r < 4; ++r) {
                const int row = rt*16 + g*4 + r;
                float h = gelu_f(ch[rt][r] + bbs);
                *(float*)(Hs + row*512 + ((colp*4) ^ ((row&15)<<4))) = h;
            }
        // h_pc = gelu(x_pc @ W_in_pc + b): 24 rows (2 row-tiles, masked)
        f32x4 cp[2];
        cp[0] = z; cp[1] = z;
        {
            bf16x8 bh = *(const bf16x8*)(wb + OFF_WINPC_H + (w*64 + lane)*8);
            bf16x8 bl = *(const bf16x8*)(wb + OFF_WINPC_L + (w*64 + lane)*8);
            #pragma unroll
            for (int rt = 0; rt < 2; ++rt) {
                const int row = rt*16 + lr;
                bf16x8 ah = bzero(), al = bzero();
                if (g < 2 && row < PCN) xfrag(x_pc + (b*PCN + row)*FEAT, g, ah, al);
                cp[rt] = MFMA(ah, bh, cp[rt]);
                cp[rt] = MFMA(al, bh, cp[rt]);
                cp[rt] = MFMA(ah, bl, cp[rt]);
            }
        }
        const float bbp = b_in_pc[colp];
        #pragma unroll
        for (int rt = 0; rt < 2; ++rt)
            #pragma unroll
            for (int r = 0; r < 4; ++r) {
                const int row = rt*16 + g*4 + r;
                if (row < PCN) {
                    float h = gelu_f(cp[rt][r] + bbp);
                    *(u16*)(Hp + row*256 + ((colp*2) ^ ((row&15)<<4))) = f2b(h);
                }
            }
    }
    __syncthreads();

    // ---- ph4: adj gather (fp32) -> A hi/lo ----
    {
        const int d = t >> 3, cq8 = t & 7;
        float acc[16];
        #pragma unroll
        for (int i = 0; i < 16; ++i) acc[i] = 0.f;
        gather_f32_8(Hs, srt_a, rs_a[d], rs_a[d+1], cq8, acc);
        writeA_8(Ah, Al, d, cq8, acc);
    }
    __syncthreads();

    // ---- ph5: GEMM1a: c1 += A_adj @ W_adj (1 ntile/wave) ----
    f32x4 c1[1][4];
    {
        const f32x4 z = {0.f,0.f,0.f,0.f};
        #pragma unroll
        for (int rt = 0; rt < 4; ++rt) c1[0][rt] = z;
    }
    gemm_nt<1,4>(Ah, Al, wb + OFF_WADJ_H, wb + OFF_WADJ_L, w, lane, g, lr, c1);
    __syncthreads();

    // ---- ph6: occ gather (bf16 hi) -> A hi/lo ----
    {
        const int d = t >> 3, cq8 = t & 7;
        float acc[16];
        #pragma unroll
        for (int i = 0; i < 16; ++i) acc[i] = 0.f;
        gather_b16_8(Hp, srt_o, rs_o[d], rs_o[d+1], cq8, acc);
        writeA_8(Ah, Al, d, cq8, acc);
    }
    __syncthreads();

    // ---- ph7: GEMM1b: c1 += A_occ @ W_occ ----
    gemm_nt<1,4>(Ah, Al, wb + OFF_WOCC_H, wb + OFF_WOCC_L, w, lane, g, lr, c1);
    __syncthreads();

    // ---- ph8: epi1: h2 = gelu(h + agg) -> A hi/lo ----
    {
        const int colp = w*16 + lr;
        #pragma unroll
        for (int rt = 0; rt < 4; ++rt)
            #pragma unroll
            for (int r = 0; r < 4; ++r) {
                const int row = rt*16 + g*4 + r;
                float hv = *(const float*)(Hs + row*512 + ((colp*4) ^ ((row&15)<<4)));
                float h2 = gelu_f(c1[0][rt][r] + hv);
                u16 hh, ll; split2(h2, hh, ll);
                const int bo = row*256 + ((colp*2) ^ ((row&15)<<4));
                *(u16*)(Ah + bo) = hh;
                *(u16*)(Al + bo) = ll;
            }
    }
    __syncthreads();

    // ---- ph9: GEMM2 (W_out, 2 ntiles/wave) + colsum/64 ----
    f32x4 c2[2][4];
    {
        const f32x4 z = {0.f,0.f,0.f,0.f};
        #pragma unroll
        for (int n = 0; n < 2; ++n)
            #pragma unroll
            for (int rt = 0; rt < 4; ++rt) c2[n][rt] = z;
    }
    gemm_nt<2,4>(Ah, Al, wb + OFF_WOUT_H, wb + OFF_WOUT_L, w*2, lane, g, lr, c2);
    #pragma unroll
    for (int ntl = 0; ntl < 2; ++ntl) {
        const int col = (w*2 + ntl)*16 + lr;
        const float bias = b_out[col];
        float cs = 0.f;
        #pragma unroll
        for (int rt = 0; rt < 4; ++rt)
            #pragma unroll
            for (int r = 0; r < 4; ++r) cs += gelu_f(c2[ntl][rt][r] + bias);
        cs += __shfl_xor(cs, 16);
        cs += __shfl_xor(cs, 32);
        if (lane < 16) shared_sq[b*DOUT + col] = cs * (1.0f/64.0f);
    }
}

// ---------------------------------------------------------------------------
// piece-path device function (512 threads, 2 batches/block)
// ---------------------------------------------------------------------------
__device__ __forceinline__ void pc_path(
    unsigned char* SMb, int pcb, int t,
    const float* __restrict__ x_sq, const float* __restrict__ x_pc,
    const float* __restrict__ b_in_sq, const float* __restrict__ b_in_pc,
    const float* __restrict__ b_out,
    const int* __restrict__ ei_att, const int* __restrict__ ei_def,
    const int* __restrict__ ei_rev,
    const u16* __restrict__ wb, float* __restrict__ shared_pc)
{
    unsigned char* Hp = SMb + PHP_OFF;
    unsigned char* Ah = SMb + PAH_OFF;
    unsigned char* Al = SMb + PAL_OFF;
    int* ea_pk = (int*)(SMb + PEA_OFF);
    int* ed_pk = (int*)(SMb + PED_OFF);
    int* srt_a = (int*)(SMb + PSA_OFF);
    int* srt_d = (int*)(SMb + PSD_OFF);
    int* rs_a  = (int*)(SMb + PRSA_OFF);
    int* cur_a = (int*)(SMb + PCUA_OFF);
    int* cnt_a = (int*)(SMb + PCNA_OFF);
    int* rs_d  = (int*)(SMb + PRSD_OFF);
    int* cur_d = (int*)(SMb + PCUD_OFF);
    int* cnt_d = (int*)(SMb + PCND_OFF);
    int* rv_s  = (int*)(SMb + PRVS_OFF);
    int* rv_d  = (int*)(SMb + PRVD_OFF);

    const int w = t >> 6, lane = t & 63, g = lane >> 4, lr = lane & 15;
    const int NR = 2*PCN;   // 48

    // ---- ph0 ----
    for (int i = t; i < 2*E_ATT; i += 512) {
        int sb = (i >= E_ATT) ? 1 : 0;
        int e = i - sb*E_ATT;
        int gb = pcb*2 + sb;
        int ro = sb*PCN - gb*PCN;
        int s = ei_att[gb*E_ATT + e] + ro;
        int d = ei_att[E_ATT_TOT + gb*E_ATT + e] + ro;
        ea_pk[i] = s | (d << 16);
        s = ei_def[gb*E_ATT + e] + ro;
        d = ei_def[E_ATT_TOT + gb*E_ATT + e] + ro;
        ed_pk[i] = s | (d << 16);
    }
    if (t < NR) {
        int sb = (t >= PCN) ? 1 : 0;
        int gb = pcb*2 + sb;
        int p = t - sb*PCN;
        rv_s[t] = ei_rev[gb*PCN + p];
        rv_d[t] = ei_rev[NPCT + gb*PCN + p] - gb*PCN + sb*PCN;
    }
    if (t < 64) { cnt_a[t] = 0; cnt_d[t] = 0; }
    __syncthreads();

    // ---- ph1: counts ----
    for (int i = t; i < 2*E_ATT; i += 512) {
        atomicAdd(&cnt_a[ea_pk[i] >> 16], 1);
        atomicAdd(&cnt_d[ed_pk[i] >> 16], 1);
    }
    __syncthreads();

    // ---- ph2: scans ----
    if (t < 64) {
        int v = cnt_a[t], o0 = v;
        for (int o = 1; o < 64; o <<= 1) { int u = __shfl_up(v, o); if (t >= o) v += u; }
        rs_a[t+1] = v; cur_a[t] = v - o0; if (t == 0) rs_a[0] = 0;
    } else if (t < 128) {
        int l = t - 64;
        int v = cnt_d[l], o0 = v;
        for (int o = 1; o < 64; o <<= 1) { int u = __shfl_up(v, o); if (l >= o) v += u; }
        rs_d[l+1] = v; cur_d[l] = v - o0; if (l == 0) rs_d[0] = 0;
    }
    __syncthreads();

    // ---- ph3: place + MFMA input-GEMMs (hp -> Hp fp32; hrev -> A hi/lo) ----
    for (int i = t; i < 2*E_ATT; i += 512) {
        int pk = ea_pk[i];
        int p = atomicAdd(&cur_a[pk >> 16], 1); srt_a[p] = pk & 0xffff;
        pk = ed_pk[i];
        p = atomicAdd(&cur_d[pk >> 16], 1); srt_d[p] = pk & 0xffff;
    }
    {
        const int colp = w*16 + lr;
        const f32x4 z = {0.f,0.f,0.f,0.f};
        // hp = gelu(x_pc @ W_in_pc + b): 48 rows (3 row-tiles)
        f32x4 cp[3];
        #pragma unroll
        for (int rt = 0; rt < 3; ++rt) cp[rt] = z;
        {
            bf16x8 bh = *(const bf16x8*)(wb + OFF_WINPC_H + (w*64 + lane)*8);
            bf16x8 bl = *(const bf16x8*)(wb + OFF_WINPC_L + (w*64 + lane)*8);
            #pragma unroll
            for (int rt = 0; rt < 3; ++rt) {
                bf16x8 ah = bzero(), al = bzero();
                if (g < 2) xfrag(x_pc + (pcb*NR + rt*16 + lr)*FEAT, g, ah, al);
                cp[rt] = MFMA(ah, bh, cp[rt]);
                cp[rt] = MFMA(al, bh, cp[rt]);
                cp[rt] = MFMA(ah, bl, cp[rt]);
            }
        }
        const float bbp = b_in_pc[colp];
        #pragma unroll
        for (int rt = 0; rt < 3; ++rt)
            #pragma unroll
            for (int r = 0; r < 4; ++r) {
                const int row = rt*16 + g*4 + r;
                float h = gelu_f(cp[rt][r] + bbp);
                *(float*)(Hp + row*512 + ((colp*4) ^ ((row&15)<<4))) = h;
            }
        // hrev = gelu(x_sq[rv_s] @ W_in_sq + b) -> scatter rows rv_d into A
        f32x4 cr[3];
        #pragma unroll
        for (int rt = 0; rt < 3; ++rt) cr[rt] = z;
        {
            bf16x8 bh = *(const bf16x8*)(wb + OFF_WINSQ_H + (w*64 + lane)*8);
            bf16x8 bl = *(const bf16x8*)(wb + OFF_WINSQ_L + (w*64 + lane)*8);
            #pragma unroll
            for (int rt = 0; rt < 3; ++rt) {
                bf16x8 ah = bzero(), al = bzero();
                if (g < 2) {
                    int gr = rv_s[rt*16 + lr];
                    xfrag(x_sq + gr*FEAT, g, ah, al);
                }
                cr[rt] = MFMA(ah, bh, cr[rt]);
                cr[rt] = MFMA(al, bh, cr[rt]);
                cr[rt] = MFMA(ah, bl, cr[rt]);
            }
        }
        const float bbs = b_in_sq[colp];
        #pragma unroll
        for (int rt = 0; rt < 3; ++rt)
            #pragma unroll
            for (int r = 0; r < 4; ++r) {
                const int row0 = rt*16 + g*4 + r;
                const int dr = rv_d[row0];
                float h = gelu_f(cr[rt][r] + bbs);
                u16 hh, ll; split2(h, hh, ll);
                const int bo = dr*256 + ((colp*2) ^ ((dr&15)<<4));
                *(u16*)(Ah + bo) = hh;
                *(u16*)(Al + bo) = ll;
            }
    }
    __syncthreads();

    // ---- ph5: GEMM1c: c1 += A_rev @ W_rev ----
    f32x4 c1[1][3];
    {
        const f32x4 z = {0.f,0.f,0.f,0.f};
        #pragma unroll
        for (int rt = 0; rt < 3; ++rt) c1[0][rt] = z;
    }
    gemm_nt<1,3>(Ah, Al, wb + OFF_WREV_H, wb + OFF_WREV_L, w, lane, g, lr, c1);
    __syncthreads();

    // ---- ph6: att gather -> A ----
    {
        const int d = t >> 3, cq8 = t & 7;
        if (d < NR) {
            float acc[16];
            #pragma unroll
            for (int i = 0; i < 16; ++i) acc[i] = 0.f;
            gather_f32_8(Hp, srt_a, rs_a[d], rs_a[d+1], cq8, acc);
            writeA_8(Ah, Al, d, cq8, acc);
        }
    }
    __syncthreads();

    // ---- ph7: GEMM1a (W_att) ----
    gemm_nt<1,3>(Ah, Al, wb + OFF_WATT_H, wb + OFF_WATT_L, w, lane, g, lr, c1);
    __syncthreads();

    // ---- ph8: def gather -> A ----
    {
        const int d = t >> 3, cq8 = t & 7;
        if (d < NR) {
            float acc[16];
            #pragma unroll
            for (int i = 0; i < 16; ++i) acc[i] = 0.f;
            gather_f32_8(Hp, srt_d, rs_d[d], rs_d[d+1], cq8, acc);
            writeA_8(Ah, Al, d, cq8, acc);
        }
    }
    __syncthreads();

    // ---- ph9: GEMM1b (W_def) ----
    gemm_nt<1,3>(Ah, Al, wb + OFF_WDEF_H, wb + OFF_WDEF_L, w, lane, g, lr, c1);
    __syncthreads();

    // ---- ph10: epi1: h2 = gelu(hp + agg) -> A ----
    {
        const int colp = w*16 + lr;
        #pragma unroll
        for (int rt = 0; rt < 3; ++rt)
            #pragma unroll
            for (int r = 0; r < 4; ++r) {
                const int row = rt*16 + g*4 + r;
                float hv = *(const float*)(Hp + row*512 + ((colp*4) ^ ((row&15)<<4)));
                float h2 = gelu_f(c1[0][rt][r] + hv);
                u16 hh, ll; split2(h2, hh, ll);
                const int bo = row*256 + ((colp*2) ^ ((row&15)<<4));
                *(u16*)(Ah + bo) = hh;
                *(u16*)(Al + bo) = ll;
            }
    }
    __syncthreads();

    // ---- ph11: GEMM2 (W_out, 2 ntiles/wave) + per-sub-batch colsum/24 ----
    f32x4 c2[2][3];
    {
        const f32x4 z = {0.f,0.f,0.f,0.f};
        #pragma unroll
        for (int n = 0; n < 2; ++n)
            #pragma unroll
            for (int rt = 0; rt < 3; ++rt) c2[n][rt] = z;
    }
    gemm_nt<2,3>(Ah, Al, wb + OFF_WOUT_H, wb + OFF_WOUT_L, w*2, lane, g, lr, c2);
    #pragma unroll
    for (int ntl = 0; ntl < 2; ++ntl) {
        const int col = (w*2 + ntl)*16 + lr;
        const float bias = b_out[col];
        float s0 = 0.f, s1 = 0.f;
        #pragma unroll
        for (int r = 0; r < 4; ++r) s0 += gelu_f(c2[ntl][0][r] + bias);
        {
            float tt = 0.f;
            #pragma unroll
            for (int r = 0; r < 4; ++r) tt += gelu_f(c2[ntl][1][r] + bias);
            s0 += (g < 2) ? tt : 0.f;
            s1 += (g < 2) ? 0.f : tt;
        }
        #pragma unroll
        for (int r = 0; r < 4; ++r) s1 += gelu_f(c2[ntl][2][r] + bias);
        s0 += __shfl_xor(s0, 16); s0 += __shfl_xor(s0, 32);
        s1 += __shfl_xor(s1, 16); s1 += __shfl_xor(s1, 32);
        if (lane < 16) {
            const int b0 = pcb*2, b1 = b0 + 1;
            shared_pc[b0*DOUT + col] = s0 * (1.0f/PCN);
            shared_pc[b1*DOUT + col] = s1 * (1.0f/PCN);
        }
    }
}

// ---------------------------------------------------------------------------
// k_main: fused square+piece pipelines. grid 3072, 512 threads, 75KB dyn LDS.
// blocks interleaved {sq, sq, pc} for dispatch mixing.
// ---------------------------------------------------------------------------
__global__ __launch_bounds__(512, 4) void k_main(
    const float* __restrict__ x_sq, const float* __restrict__ x_pc,
    const float* __restrict__ b_in_sq, const float* __restrict__ b_in_pc,
    const float* __restrict__ b_out,
    const int* __restrict__ ei_adj, const int* __restrict__ ei_occ,
    const int* __restrict__ ei_att, const int* __restrict__ ei_def,
    const int* __restrict__ ei_rev,
    const u16* __restrict__ wb,
    float* __restrict__ shared_sq, float* __restrict__ shared_pc)
{
    extern __shared__ __align__(16) unsigned char SMb[];
    const int bid = blockIdx.x;
    const int grp = bid / 3, rem = bid - grp*3;
    if (rem < 2) {
        sq_path(SMb, grp*2 + rem, threadIdx.x, x_sq, x_pc, b_in_sq, b_in_pc,
                b_out, ei_adj, ei_occ, wb, shared_sq);
    } else {
        pc_path(SMb, grp, threadIdx.x, x_sq, x_pc, b_in_sq, b_in_pc,
                b_out, ei_att, ei_def, ei_rev, wb, shared_pc);
    }
}

// ---------------------------------------------------------------------------
// k_head: tpol(hi/lo bf16) = gelu(shared@W_pt+b); value head fp32
// ---------------------------------------------------------------------------
__global__ __launch_bounds__(256) void k_head(
    const float* __restrict__ shared_sq, const float* __restrict__ shared_pc,
    const float* __restrict__ W_pt, const float* __restrict__ b_pt,
    const float* __restrict__ W_vt, const float* __restrict__ b_vt,
    const float* __restrict__ W_vh, const float* __restrict__ b_vh,
    u16* __restrict__ tpol_h, u16* __restrict__ tpol_l, float* __restrict__ out_value)
{
    __shared__ float sh[2*DOUT];
    __shared__ float vred[2*TDIM];
    const int t = threadIdx.x;
    const int hh = t >> 7, j = t & 127;
    const int b = blockIdx.x*2 + hh;
    for (int i = t; i < 2*DOUT; i += 256)
        sh[i] = shared_sq[blockIdx.x*2*DOUT + i] + shared_pc[blockIdx.x*2*DOUT + i];
    __syncthreads();
    const float* s = sh + hh*DOUT;
    float ap = b_pt[j], av = b_vt[j];
    #pragma unroll 8
    for (int k = 0; k < DOUT; ++k) {
        float sv = s[k];
        ap += sv * W_pt[k*TDIM + j];
        av += sv * W_vt[k*TDIM + j];
    }
    float tv = gelu_f(ap);
    u16 th, tl; split2(tv, th, tl);
    tpol_h[b*TDIM + j] = th;
    tpol_l[b*TDIM + j] = tl;
    vred[hh*TDIM + j] = gelu_f(av) * W_vh[j];
    __syncthreads();
    for (int stp = 64; stp > 0; stp >>= 1) {
        if (j < stp) vred[hh*TDIM + j] += vred[hh*TDIM + j + stp];
        __syncthreads();
    }
    if (j == 0) out_value[b] = tanhf(vred[hh*TDIM] + b_vh[0]);
}

// ---------------------------------------------------------------------------
// k_pol: policy = tpol @ W_ph + b_ph, split-bf16 MFMA. grid (73, 32).
// ---------------------------------------------------------------------------
__global__ __launch_bounds__(256) void k_pol(
    const u16* __restrict__ tpol_h, const u16* __restrict__ tpol_l,
    const u16* __restrict__ wb, const float* __restrict__ b_ph,
    float* __restrict__ pol)
{
    const u16* wph_h = wb + OFF_WPH_H;
    const u16* wph_l = wb + OFF_WPH_L;
    const int t = threadIdx.x, w = t >> 6, lane = t & 63, g = lane >> 4, lr = lane & 15;
    const int nt = blockIdx.x*4 + w;       // 0..291
    const int rbase = blockIdx.y*64;
    f32x4 acc[4];
    const f32x4 z = {0.f,0.f,0.f,0.f};
    #pragma unroll
    for (int rt = 0; rt < 4; ++rt) acc[rt] = z;
    #pragma unroll
    for (int ks = 0; ks < 4; ++ks) {
        bf16x8 bh = *(const bf16x8*)(wph_h + ((nt*4 + ks)*64 + lane)*8);
        bf16x8 bl = *(const bf16x8*)(wph_l + ((nt*4 + ks)*64 + lane)*8);
        #pragma unroll
        for (int rt = 0; rt < 4; ++rt) {
            const int ro = (rbase + rt*16 + lr)*TDIM + ks*32 + g*8;
            bf16x8 ah = *(const bf16x8*)(tpol_h + ro);
            bf16x8 al = *(const bf16x8*)(tpol_l + ro);
            acc[rt] = MFMA(ah, bh, acc[rt]);
            acc[rt] = MFMA(al, bh, acc[rt]);
            acc[rt] = MFMA(ah, bl, acc[rt]);
        }
    }
    const float bias = b_ph[nt*16 + lr];
    #pragma unroll
    for (int rt = 0; rt < 4; ++rt)
        #pragma unroll
        for (int r = 0; r < 4; ++r) {
            int row = rbase + rt*16 + g*4 + r;
            pol[(size_t)row*ADIM + nt*16 + lr] = acc[rt][r] + bias;
        }
}

// ---------------------------------------------------------------------------
extern "C" void kernel_launch(void* const* d_in, const int* in_sizes, int n_in,
                              void* d_out, int out_size, void* d_ws, size_t ws_size,
                              hipStream_t stream) {
    (void)in_sizes; (void)n_in; (void)out_size; (void)ws_size;
    const float* x_sq    = (const float*)d_in[0];
    const float* x_pc    = (const float*)d_in[1];
    const float* W_in_sq = (const float*)d_in[2];
    const float* b_in_sq = (const float*)d_in[3];
    const float* W_in_pc = (const float*)d_in[4];
    const float* b_in_pc = (const float*)d_in[5];
    const float* W_adj   = (const float*)d_in[6];
    const float* W_occ   = (const float*)d_in[7];
    const float* W_att   = (const float*)d_in[8];
    const float* W_def   = (const float*)d_in[9];
    const float* W_rev   = (const float*)d_in[10];
    const float* W_out   = (const float*)d_in[11];
    const float* b_out   = (const float*)d_in[12];
    const float* W_pt    = (const float*)d_in[13];
    const float* b_pt    = (const float*)d_in[14];
    const float* W_vt    = (const float*)d_in[15];
    const float* b_vt    = (const float*)d_in[16];
    const float* W_ph    = (const float*)d_in[17];
    const float* b_ph    = (const float*)d_in[18];
    const float* W_vh    = (const float*)d_in[19];
    const float* b_vh    = (const float*)d_in[20];
    const int* ei_adj    = (const int*)d_in[21];
    const int* ei_occ    = (const int*)d_in[22];
    const int* ei_att    = (const int*)d_in[23];
    const int* ei_def    = (const int*)d_in[24];
    const int* ei_rev    = (const int*)d_in[25];

    float* out = (float*)d_out;
    float* pol = out;
    float* val = out + (size_t)BATCH * ADIM;

    float* shared_sq = (float*)d_ws;                     // [2048][256] f32
    float* shared_pc = shared_sq + BATCH*DOUT;           // [2048][256] f32
    u16* tpol_h = (u16*)(shared_pc + BATCH*DOUT);        // [2048][128] bf16
    u16* tpol_l = tpol_h + BATCH*TDIM;
    u16* wb     = tpol_l + BATCH*TDIM;                   // WB_TOTAL u16

    hipFuncSetAttribute((const void*)k_main,
                        hipFuncAttributeMaxDynamicSharedMemorySize, KSQ_SMEM);

    k_prep<<<352, 256, 0, stream>>>(W_adj, W_occ, W_att, W_def, W_rev, W_out, W_ph,
                                    W_in_sq, W_in_pc, wb);
    k_main<<<3072, 512, KSQ_SMEM, stream>>>(x_sq, x_pc, b_in_sq, b_in_pc, b_out,
                                            ei_adj, ei_occ, ei_att, ei_def, ei_rev,
                                            wb, shared_sq, shared_pc);
    k_head<<<BATCH/2, 256, 0, stream>>>(shared_sq, shared_pc, W_pt, b_pt, W_vt, b_vt,
                                        W_vh, b_vh, tpol_h, tpol_l, val);
    k_pol<<<dim3(ADIM/64, BATCH/64), 256, 0, stream>>>(tpol_h, tpol_l, wb, b_ph, pol);
}

// Round 6
// 198.207 us; speedup vs baseline: 5.5755x; 1.1443x over previous
//
#include <hip/hip_runtime.h>

#define BATCH 2048
#define SQN 64
#define PCN 24
#define FEAT 16
#define HID 128
#define DOUT 256
#define TDIM 128
#define ADIM 4672
#define NSQT (BATCH*SQN)
#define NPCT (BATCH*PCN)
#define E_ADJ 420
#define E_ATT 40
#define E_ADJ_TOT (BATCH*E_ADJ)
#define E_ATT_TOT (BATCH*E_ATT)

typedef unsigned short u16;
typedef unsigned int u32;
typedef __attribute__((ext_vector_type(8))) short bf16x8;
typedef __attribute__((ext_vector_type(8))) unsigned short u16x8;
typedef __attribute__((ext_vector_type(4))) float f32x4;
typedef __attribute__((ext_vector_type(2))) unsigned int u32x2;
typedef __attribute__((ext_vector_type(4))) unsigned int u32x4;

// ---- weight fragment buffer offsets (u16 units), hi/lo split ----
#define OFF_WADJ_H 0
#define OFF_WADJ_L 16384
#define OFF_WOCC_H 32768
#define OFF_WOCC_L 49152
#define OFF_WATT_H 65536
#define OFF_WATT_L 81920
#define OFF_WDEF_H 98304
#define OFF_WDEF_L 114688
#define OFF_WREV_H 131072
#define OFF_WREV_L 147456
#define OFF_WOUT_H 163840
#define OFF_WOUT_L 196608
#define OFF_WPH_H  229376
#define OFF_WPH_L  827392
#define OFF_WINSQ_H 1425408
#define OFF_WINSQ_L 1429504
#define OFF_WINPC_H 1433600
#define OFF_WINPC_L 1437696
#define WB_TOTAL    1441792

#define K_SMEM 81920

// ---- k_pc LDS layout (within same dynamic buffer) ----
#define PHP_OFF  0        // [48][512B] fp32 swizzled
#define PAH_OFF  24576    // [48][256B]
#define PAL_OFF  36864    // [48][256B]
#define PEA_OFF  49152    // 80 packed att
#define PED_OFF  49472    // 80 packed def
#define PSA_OFF  49792    // 80
#define PSD_OFF  50112    // 80
#define PRSA_OFF 50432    // 65
#define PCUA_OFF 50692    // 64
#define PCNA_OFF 50948    // 64
#define PRSD_OFF 51204    // 65
#define PCUD_OFF 51464    // 64
#define PCND_OFF 51720    // 64
#define PRVS_OFF 51976    // 48
#define PRVD_OFF 52168    // 48

// ---- fast helpers ----
__device__ __forceinline__ u32 cvtpk(float a, float b) {
    u32 r;
    asm("v_cvt_pk_bf16_f32 %0, %1, %2" : "=v"(r) : "v"(a), "v"(b));
    return r;   // lo half = bf16(a), hi half = bf16(b), RNE
}
__device__ __forceinline__ u16 f2b(float x) { return (u16)cvtpk(x, x); }
__device__ __forceinline__ float b2f(u16 h) { return __uint_as_float(((u32)h) << 16); }
__device__ __forceinline__ void split2(float x, u16& h, u16& l) {
    u32 wp = cvtpk(x, x);
    h = (u16)wp;
    float r = x - __uint_as_float(wp << 16);
    l = (u16)cvtpk(r, r);
}
__device__ __forceinline__ void split_pk(float a, float b, u32& wh, u32& wl) {
    wh = cvtpk(a, b);
    float ra = a - __uint_as_float(wh << 16);
    float rb = b - __uint_as_float(wh & 0xffff0000u);
    wl = cvtpk(ra, rb);
}
__device__ __forceinline__ float gelu_f(float x) {
    // x * sigmoid(2z), z = 0.79788456(x + 0.044715 x^3); == tanh-gelu exactly
    float x2 = x * x;
    float z2 = x * __builtin_fmaf(x2, 0.0713548162f, 1.5957691216f);
    float e = __expf(z2);
    return x - x * __fdividef(1.0f, e + 1.0f);
}
__device__ __forceinline__ f32x4 MFMA(bf16x8 a, bf16x8 b, f32x4 c) {
    return __builtin_amdgcn_mfma_f32_16x16x32_bf16(a, b, c, 0, 0, 0);
}
__device__ __forceinline__ bf16x8 bzero() {
    bf16x8 v = {0,0,0,0,0,0,0,0}; return v;
}
// build hi/lo A-frag from a 16-float global row (g<2 callers only)
__device__ __forceinline__ void xfrag(const float* __restrict__ xrow, int g,
                                      bf16x8& ah, bf16x8& al)
{
    const f32x4 a = *(const f32x4*)(xrow + g*8);
    const f32x4 b = *(const f32x4*)(xrow + g*8 + 4);
    u32 h0,h1,h2,h3,l0,l1,l2,l3;
    split_pk(a[0], a[1], h0, l0);
    split_pk(a[2], a[3], h1, l1);
    split_pk(b[0], b[1], h2, l2);
    split_pk(b[2], b[3], h3, l3);
    u32x4 vh = {h0,h1,h2,h3};
    u32x4 vl = {l0,l1,l2,l3};
    ah = *(bf16x8*)&vh;
    al = *(bf16x8*)&vl;
}

// GEMM over K=128, NT n-tiles per wave starting ntBase, split-bf16 3-term.
template<int NT, int RT>
__device__ __forceinline__ void gemm_nt(
    const unsigned char* Ah, const unsigned char* Al,
    const u16* __restrict__ wh, const u16* __restrict__ wl,
    int ntBase, int lane, int g, int lr, f32x4 (&c)[NT][RT])
{
    const int sw = lr << 4;
    #pragma unroll
    for (int ks = 0; ks < 4; ++ks) {
        const int ko = ks*64 + g*16;
        bf16x8 ah[RT], al[RT];
        #pragma unroll
        for (int rt = 0; rt < RT; ++rt) {
            const int ro = (rt*16 + lr)*256 + (ko ^ sw);
            ah[rt] = *(const bf16x8*)(Ah + ro);
            al[rt] = *(const bf16x8*)(Al + ro);
        }
        #pragma unroll
        for (int ntl = 0; ntl < NT; ++ntl) {
            bf16x8 bh = *(const bf16x8*)(wh + (((ntBase+ntl)*4 + ks)*64 + lane)*8);
            bf16x8 bl = *(const bf16x8*)(wl + (((ntBase+ntl)*4 + ks)*64 + lane)*8);
            #pragma unroll
            for (int rt = 0; rt < RT; ++rt) {
                c[ntl][rt] = MFMA(ah[rt], bh, c[ntl][rt]);
                c[ntl][rt] = MFMA(al[rt], bh, c[ntl][rt]);
                c[ntl][rt] = MFMA(ah[rt], bl, c[ntl][rt]);
            }
        }
    }
}

// 512-thread gather: thread owns (dst row d, 1/8 of the 128-col row)
__device__ __forceinline__ void gather_f32_8(
    const unsigned char* H, const int* srt, int st, int en, int cq8, float (&acc)[16])
{
    for (int i = st; i < en; ++i) {
        const int s = srt[i];
        const unsigned char* rp = H + s*512;
        const int sw2 = (s & 15) << 4;
        #pragma unroll
        for (int u = 0; u < 4; ++u) {
            f32x4 v = *(const f32x4*)(rp + ((cq8*64 + u*16) ^ sw2));
            acc[u*4+0] += v[0]; acc[u*4+1] += v[1];
            acc[u*4+2] += v[2]; acc[u*4+3] += v[3];
        }
    }
}
__device__ __forceinline__ void writeA_8(
    unsigned char* Ah, unsigned char* Al, int d, int cq8, const float (&acc)[16])
{
    unsigned char* wh = Ah + d*256;
    unsigned char* wl = Al + d*256;
    const int dw = (d & 15) << 4;
    #pragma unroll
    for (int u = 0; u < 2; ++u) {
        u32 oh[4], ol[4];
        #pragma unroll
        for (int j = 0; j < 4; ++j)
            split_pk(acc[u*8 + j*2], acc[u*8 + j*2 + 1], oh[j], ol[j]);
        u32x4 vh = {oh[0], oh[1], oh[2], oh[3]};
        u32x4 vl = {ol[0], ol[1], ol[2], ol[3]};
        *(u32x4*)(wh + ((cq8*32 + u*16) ^ dw)) = vh;
        *(u32x4*)(wl + ((cq8*32 + u*16) ^ dw)) = vl;
    }
}

// ---------------------------------------------------------------------------
// k_prep: fragment-major hi/lo bf16 weight buffers.
// frag (nt,kb): lane l elem j -> W[k = kb*32 + (l>>4)*8 + j][col = nt*16 + (l&15)]
// ---------------------------------------------------------------------------
__global__ __launch_bounds__(256) void k_prep(
    const float* __restrict__ W_adj, const float* __restrict__ W_occ,
    const float* __restrict__ W_att, const float* __restrict__ W_def,
    const float* __restrict__ W_rev, const float* __restrict__ W_out,
    const float* __restrict__ W_ph,
    const float* __restrict__ W_in_sq, const float* __restrict__ W_in_pc,
    u16* __restrict__ wb)
{
    int gid = blockIdx.x*256 + threadIdx.x;     // 352*256 -> 1408 frags
    int fid = gid >> 6, lane = gid & 63;
    int g8 = (lane >> 4) * 8, lr = lane & 15;
    u16x8 vh, vl;
    if (fid >= 1392) {   // W_in_sq / W_in_pc: K=16 padded to 32
        int f = fid - 1392;
        const float* src = (f < 8) ? W_in_sq : W_in_pc;
        int oh = (f < 8) ? OFF_WINSQ_H : OFF_WINPC_H;
        int ol = (f < 8) ? OFF_WINSQ_L : OFF_WINPC_L;
        int nt = f & 7;
        int col = nt*16 + lr;
        #pragma unroll
        for (int j = 0; j < 8; ++j) {
            int k = g8 + j;
            float v = (k < 16) ? src[k*HID + col] : 0.f;
            u16 h, l; split2(v, h, l);
            vh[j] = h; vl[j] = l;
        }
        *(u16x8*)(wb + oh + (nt*64 + lane)*8) = vh;
        *(u16x8*)(wb + ol + (nt*64 + lane)*8) = vl;
        return;
    }
    const float* src; int ld, f, oh, ol;
    if (fid < 32)       { src = W_adj; ld = HID;  f = fid;      oh = OFF_WADJ_H; ol = OFF_WADJ_L; }
    else if (fid < 64)  { src = W_occ; ld = HID;  f = fid-32;   oh = OFF_WOCC_H; ol = OFF_WOCC_L; }
    else if (fid < 96)  { src = W_att; ld = HID;  f = fid-64;   oh = OFF_WATT_H; ol = OFF_WATT_L; }
    else if (fid < 128) { src = W_def; ld = HID;  f = fid-96;   oh = OFF_WDEF_H; ol = OFF_WDEF_L; }
    else if (fid < 160) { src = W_rev; ld = HID;  f = fid-128;  oh = OFF_WREV_H; ol = OFF_WREV_L; }
    else if (fid < 224) { src = W_out; ld = DOUT; f = fid-160;  oh = OFF_WOUT_H; ol = OFF_WOUT_L; }
    else                { src = W_ph;  ld = ADIM; f = fid-224;  oh = OFF_WPH_H;  ol = OFF_WPH_L; }
    int nt = f >> 2, kb = f & 3;
    int col = nt*16 + lr;
    #pragma unroll
    for (int j = 0; j < 8; ++j) {
        int k = kb*32 + g8 + j;
        u16 h, l; split2(src[k*ld + col], h, l);
        vh[j] = h; vl[j] = l;
    }
    *(u16x8*)(wb + oh + (f*64 + lane)*8) = vh;
    *(u16x8*)(wb + ol + (f*64 + lane)*8) = vl;
}

// ---------------------------------------------------------------------------
// square-path: segment-sums as M-matrix MFMA (agg = M @ (h @ W)).
// LDS (81920B): [0,32K) Hs hi/lo -> HWadjT hi/lo ; [32K,64K) Mint -> HWoccT+Mocc -> A hi/lo ;
//               [64K,72K) M_adj ; [72K,80K) Hp(32 rows, bf16-hi)
// ---------------------------------------------------------------------------
__device__ __forceinline__ void sq_path(
    unsigned char* SMb, int b, int t,
    const float* __restrict__ x_sq, const float* __restrict__ x_pc,
    const float* __restrict__ b_in_sq, const float* __restrict__ b_in_pc,
    const float* __restrict__ b_out,
    const int* __restrict__ ei_adj, const int* __restrict__ ei_occ,
    const u16* __restrict__ wb, float* __restrict__ shared_sq)
{
    unsigned char* Hs_h  = SMb;             // [64][256B] swz15 (later HWadjT_h [128][128B] swz7)
    unsigned char* Hs_l  = SMb + 16384;     //                (later HWadjT_l)
    int*           Mint  = (int*)(SMb + 32768);  // [64][64] i32 (early)
    unsigned char* HOT_h = SMb + 32768;     // [128][64B] swz3
    unsigned char* HOT_l = SMb + 40960;
    unsigned char* Mocc  = SMb + 49152;     // [64][64B] swz3 bf16
    unsigned char* A_h   = SMb + 32768;     // [64][256B] swz15 (epi1+)
    unsigned char* A_l   = SMb + 49152;
    unsigned char* Madj  = SMb + 65536;     // [64][128B] swz7 bf16
    unsigned char* Hp    = SMb + 73728;     // [32][256B] swz15 bf16-hi (rows 24-31 zero)

    const int w = t >> 6, lane = t & 63, g = lane >> 4, lr = lane & 15;
    const int colp = w*16 + lr;

    // ---- ph0: zero Mint / Mocc / Hp pad rows ----
    #pragma unroll
    for (int i = 0; i < 8; ++i) Mint[t + i*512] = 0;
    ((u32*)Mocc)[t] = 0;
    ((u32*)Mocc)[t + 512] = 0;
    ((u32*)(Hp + 6144))[t] = 0;
    __syncthreads();  // B0

    // ---- ph0b: build count matrices ----
    for (int i = t; i < E_ADJ; i += 512) {
        int s = ei_adj[b*E_ADJ + i] - b*SQN;
        int d = ei_adj[E_ADJ_TOT + b*E_ADJ + i] - b*SQN;
        atomicAdd(&Mint[d*64 + s], 1);
    }
    if (t < PCN) {
        int p = ei_occ[b*PCN + t] - b*PCN;
        int d = ei_occ[NPCT + b*PCN + t] - b*SQN;
        *(u16*)(Mocc + d*64 + ((p*2) ^ ((d&3)<<4))) = 0x3F80;  // bf16 1.0
    }
    __syncthreads();  // B1

    // ---- ph1: Mint -> Madj (bf16 swz7) ; input GEMMs -> Hs hi/lo, Hp hi ----
    #pragma unroll
    for (int ii = 0; ii < 4; ++ii) {
        int i = t + ii*512;              // 0..2047 (64 rows x 32 col-pairs)
        int row = i >> 5, cp = i & 31;
        float v0 = (float)Mint[row*64 + cp*2];
        float v1 = (float)Mint[row*64 + cp*2 + 1];
        *(u32*)(Madj + row*128 + ((cp*4) ^ ((row&7)<<4))) = cvtpk(v0, v1);
    }
    float hv[16];   // residual h (post-gelu) kept in registers for epi1
    {
        const f32x4 z = {0.f,0.f,0.f,0.f};
        f32x4 ch[4] = {z,z,z,z};
        {
            bf16x8 bh = *(const bf16x8*)(wb + OFF_WINSQ_H + (w*64 + lane)*8);
            bf16x8 bl = *(const bf16x8*)(wb + OFF_WINSQ_L + (w*64 + lane)*8);
            #pragma unroll
            for (int rt = 0; rt < 4; ++rt) {
                bf16x8 ah = bzero(), al = bzero();
                if (g < 2) xfrag(x_sq + (b*SQN + rt*16 + lr)*FEAT, g, ah, al);
                ch[rt] = MFMA(ah, bh, ch[rt]);
                ch[rt] = MFMA(al, bh, ch[rt]);
                ch[rt] = MFMA(ah, bl, ch[rt]);
            }
        }
        const float bbs = b_in_sq[colp];
        #pragma unroll
        for (int rt = 0; rt < 4; ++rt)
            #pragma unroll
            for (int r = 0; r < 4; ++r) {
                const int row = rt*16 + g*4 + r;
                float h = gelu_f(ch[rt][r] + bbs);
                hv[rt*4 + r] = h;
                u16 hh, ll; split2(h, hh, ll);
                const int bo = row*256 + ((colp*2) ^ ((row&15)<<4));
                *(u16*)(Hs_h + bo) = hh;
                *(u16*)(Hs_l + bo) = ll;
            }
        f32x4 cp2[2] = {z, z};
        {
            bf16x8 bh = *(const bf16x8*)(wb + OFF_WINPC_H + (w*64 + lane)*8);
            bf16x8 bl = *(const bf16x8*)(wb + OFF_WINPC_L + (w*64 + lane)*8);
            #pragma unroll
            for (int rt = 0; rt < 2; ++rt) {
                const int row = rt*16 + lr;
                bf16x8 ah = bzero(), al = bzero();
                if (g < 2 && row < PCN) xfrag(x_pc + (b*PCN + row)*FEAT, g, ah, al);
                cp2[rt] = MFMA(ah, bh, cp2[rt]);
                cp2[rt] = MFMA(al, bh, cp2[rt]);
                cp2[rt] = MFMA(ah, bl, cp2[rt]);
            }
        }
        const float bbp = b_in_pc[colp];
        #pragma unroll
        for (int rt = 0; rt < 2; ++rt)
            #pragma unroll
            for (int r = 0; r < 4; ++r) {
                const int row = rt*16 + g*4 + r;
                if (row < PCN) {
                    float h = gelu_f(cp2[rt][r] + bbp);
                    *(u16*)(Hp + row*256 + ((colp*2) ^ ((row&15)<<4))) = f2b(h);
                }
            }
    }
    __syncthreads();  // B2

    // ---- ph5: HW GEMMs (HW_adj = h_sq@W_adj 3-term; HW_occ = h_pc@W_occ 2-term) ----
    f32x4 hwj[4], hwo[2];
    {
        const f32x4 z = {0.f,0.f,0.f,0.f};
        hwj[0]=z; hwj[1]=z; hwj[2]=z; hwj[3]=z; hwo[0]=z; hwo[1]=z;
        const int sw15 = lr << 4;
        #pragma unroll
        for (int ks = 0; ks < 4; ++ks) {
            const int ko = ks*64 + g*16;
            bf16x8 bh = *(const bf16x8*)(wb + OFF_WADJ_H + ((w*4 + ks)*64 + lane)*8);
            bf16x8 bl = *(const bf16x8*)(wb + OFF_WADJ_L + ((w*4 + ks)*64 + lane)*8);
            #pragma unroll
            for (int rt = 0; rt < 4; ++rt) {
                const int ro = (rt*16 + lr)*256 + (ko ^ sw15);
                bf16x8 ah = *(const bf16x8*)(Hs_h + ro);
                bf16x8 al = *(const bf16x8*)(Hs_l + ro);
                hwj[rt] = MFMA(ah, bh, hwj[rt]);
                hwj[rt] = MFMA(al, bh, hwj[rt]);
                hwj[rt] = MFMA(ah, bl, hwj[rt]);
            }
            bf16x8 oh = *(const bf16x8*)(wb + OFF_WOCC_H + ((w*4 + ks)*64 + lane)*8);
            bf16x8 ol = *(const bf16x8*)(wb + OFF_WOCC_L + ((w*4 + ks)*64 + lane)*8);
            #pragma unroll
            for (int rt = 0; rt < 2; ++rt) {
                const int ro = (rt*16 + lr)*256 + (ko ^ sw15);
                bf16x8 ah = *(const bf16x8*)(Hp + ro);
                hwo[rt] = MFMA(ah, oh, hwo[rt]);
                hwo[rt] = MFMA(ah, ol, hwo[rt]);
            }
        }
    }
    __syncthreads();  // B3 (all Hs/Hp reads done)

    // ---- ph5b: write HWadjT (over Hs) + HWoccT, both transposed [j][s] ----
    {
        const int swj = (lr & 7) << 4;
        #pragma unroll
        for (int rt = 0; rt < 4; ++rt) {
            u32 h01, l01, h23, l23;
            split_pk(hwj[rt][0], hwj[rt][1], h01, l01);
            split_pk(hwj[rt][2], hwj[rt][3], h23, l23);
            const int off = colp*128 + ((rt*32 + g*8) ^ swj);
            *(u32x2*)(Hs_h + off) = (u32x2){h01, h23};
            *(u32x2*)(Hs_l + off) = (u32x2){l01, l23};
        }
        const int swo = (lr & 3) << 4;
        #pragma unroll
        for (int rt = 0; rt < 2; ++rt) {
            u32 h01, l01, h23, l23;
            split_pk(hwo[rt][0], hwo[rt][1], h01, l01);
            split_pk(hwo[rt][2], hwo[rt][3], h23, l23);
            const int off = colp*64 + ((rt*32 + g*8) ^ swo);
            *(u32x2*)(HOT_h + off) = (u32x2){h01, h23};
            *(u32x2*)(HOT_l + off) = (u32x2){l01, l23};
        }
    }
    __syncthreads();  // B4

    // ---- ph6: M-GEMMs: c1 = M_adj@HWadjT + M_occ@HWoccT ----
    f32x4 c1[4];
    {
        const f32x4 z = {0.f,0.f,0.f,0.f};
        c1[0]=z; c1[1]=z; c1[2]=z; c1[3]=z;
        const int swj = (lr & 7) << 4;
        #pragma unroll
        for (int ks = 0; ks < 2; ++ks) {
            const int bo = colp*128 + ((ks*64 + g*16) ^ swj);
            bf16x8 bh = *(const bf16x8*)(Hs_h + bo);
            bf16x8 bl = *(const bf16x8*)(Hs_l + bo);
            #pragma unroll
            for (int rt = 0; rt < 4; ++rt) {
                const int ao = (rt*16 + lr)*128 + ((ks*64 + g*16) ^ swj);
                bf16x8 am = *(const bf16x8*)(Madj + ao);
                c1[rt] = MFMA(am, bh, c1[rt]);
                c1[rt] = MFMA(am, bl, c1[rt]);
            }
        }
        const int swo = (lr & 3) << 4;
        {
            const int bo = colp*64 + ((g*16) ^ swo);
            bf16x8 bh = *(const bf16x8*)(HOT_h + bo);
            bf16x8 bl = *(const bf16x8*)(HOT_l + bo);
            #pragma unroll
            for (int rt = 0; rt < 4; ++rt) {
                const int ao = (rt*16 + lr)*64 + ((g*16) ^ swo);
                bf16x8 am = *(const bf16x8*)(Mocc + ao);
                c1[rt] = MFMA(am, bh, c1[rt]);
                c1[rt] = MFMA(am, bl, c1[rt]);
            }
        }
    }
    __syncthreads();  // B5

    // ---- epi1: h2 = gelu(c1 + h) -> A hi/lo (residual from registers) ----
    #pragma unroll
    for (int rt = 0; rt < 4; ++rt)
        #pragma unroll
        for (int r = 0; r < 4; ++r) {
            const int row = rt*16 + g*4 + r;
            float h2 = gelu_f(c1[rt][r] + hv[rt*4 + r]);
            u16 hh, ll; split2(h2, hh, ll);
            const int bo = row*256 + ((colp*2) ^ ((row&15)<<4));
            *(u16*)(A_h + bo) = hh;
            *(u16*)(A_l + bo) = ll;
        }
    __syncthreads();  // B6

    // ---- GEMM2 (W_out, 2 ntiles/wave) + colsum/64 ----
    f32x4 c2[2][4];
    {
        const f32x4 z = {0.f,0.f,0.f,0.f};
        #pragma unroll
        for (int n = 0; n < 2; ++n)
            #pragma unroll
            for (int rt = 0; rt < 4; ++rt) c2[n][rt] = z;
    }
    gemm_nt<2,4>(A_h, A_l, wb + OFF_WOUT_H, wb + OFF_WOUT_L, w*2, lane, g, lr, c2);
    #pragma unroll
    for (int ntl = 0; ntl < 2; ++ntl) {
        const int col = (w*2 + ntl)*16 + lr;
        const float bias = b_out[col];
        float cs = 0.f;
        #pragma unroll
        for (int rt = 0; rt < 4; ++rt)
            #pragma unroll
            for (int r = 0; r < 4; ++r) cs += gelu_f(c2[ntl][rt][r] + bias);
        cs += __shfl_xor(cs, 16);
        cs += __shfl_xor(cs, 32);
        if (lane < 16) shared_sq[b*DOUT + col] = cs * (1.0f/64.0f);
    }
}

// ---------------------------------------------------------------------------
// piece-path (2 batches/block) — round-5 structure, fast helpers
// ---------------------------------------------------------------------------
__device__ __forceinline__ void pc_path(
    unsigned char* SMb, int pcb, int t,
    const float* __restrict__ x_sq, const float* __restrict__ x_pc,
    const float* __restrict__ b_in_sq, const float* __restrict__ b_in_pc,
    const float* __restrict__ b_out,
    const int* __restrict__ ei_att, const int* __restrict__ ei_def,
    const int* __restrict__ ei_rev,
    const u16* __restrict__ wb, float* __restrict__ shared_pc)
{
    unsigned char* Hp = SMb + PHP_OFF;
    unsigned char* Ah = SMb + PAH_OFF;
    unsigned char* Al = SMb + PAL_OFF;
    int* ea_pk = (int*)(SMb + PEA_OFF);
    int* ed_pk = (int*)(SMb + PED_OFF);
    int* srt_a = (int*)(SMb + PSA_OFF);
    int* srt_d = (int*)(SMb + PSD_OFF);
    int* rs_a  = (int*)(SMb + PRSA_OFF);
    int* cur_a = (int*)(SMb + PCUA_OFF);
    int* cnt_a = (int*)(SMb + PCNA_OFF);
    int* rs_d  = (int*)(SMb + PRSD_OFF);
    int* cur_d = (int*)(SMb + PCUD_OFF);
    int* cnt_d = (int*)(SMb + PCND_OFF);
    int* rv_s  = (int*)(SMb + PRVS_OFF);
    int* rv_d  = (int*)(SMb + PRVD_OFF);

    const int w = t >> 6, lane = t & 63, g = lane >> 4, lr = lane & 15;
    const int NR = 2*PCN;   // 48

    for (int i = t; i < 2*E_ATT; i += 512) {
        int sb = (i >= E_ATT) ? 1 : 0;
        int e = i - sb*E_ATT;
        int gb = pcb*2 + sb;
        int ro = sb*PCN - gb*PCN;
        int s = ei_att[gb*E_ATT + e] + ro;
        int d = ei_att[E_ATT_TOT + gb*E_ATT + e] + ro;
        ea_pk[i] = s | (d << 16);
        s = ei_def[gb*E_ATT + e] + ro;
        d = ei_def[E_ATT_TOT + gb*E_ATT + e] + ro;
        ed_pk[i] = s | (d << 16);
    }
    if (t < NR) {
        int sb = (t >= PCN) ? 1 : 0;
        int gb = pcb*2 + sb;
        int p = t - sb*PCN;
        rv_s[t] = ei_rev[gb*PCN + p];
        rv_d[t] = ei_rev[NPCT + gb*PCN + p] - gb*PCN + sb*PCN;
    }
    if (t < 64) { cnt_a[t] = 0; cnt_d[t] = 0; }
    __syncthreads();

    for (int i = t; i < 2*E_ATT; i += 512) {
        atomicAdd(&cnt_a[ea_pk[i] >> 16], 1);
        atomicAdd(&cnt_d[ed_pk[i] >> 16], 1);
    }
    __syncthreads();

    if (t < 64) {
        int v = cnt_a[t], o0 = v;
        for (int o = 1; o < 64; o <<= 1) { int u = __shfl_up(v, o); if (t >= o) v += u; }
        rs_a[t+1] = v; cur_a[t] = v - o0; if (t == 0) rs_a[0] = 0;
    } else if (t < 128) {
        int l = t - 64;
        int v = cnt_d[l], o0 = v;
        for (int o = 1; o < 64; o <<= 1) { int u = __shfl_up(v, o); if (l >= o) v += u; }
        rs_d[l+1] = v; cur_d[l] = v - o0; if (l == 0) rs_d[0] = 0;
    }
    __syncthreads();

    for (int i = t; i < 2*E_ATT; i += 512) {
        int pk = ea_pk[i];
        int p = atomicAdd(&cur_a[pk >> 16], 1); srt_a[p] = pk & 0xffff;
        pk = ed_pk[i];
        p = atomicAdd(&cur_d[pk >> 16], 1); srt_d[p] = pk & 0xffff;
    }
    {
        const int colp = w*16 + lr;
        const f32x4 z = {0.f,0.f,0.f,0.f};
        f32x4 cp[3] = {z,z,z};
        {
            bf16x8 bh = *(const bf16x8*)(wb + OFF_WINPC_H + (w*64 + lane)*8);
            bf16x8 bl = *(const bf16x8*)(wb + OFF_WINPC_L + (w*64 + lane)*8);
            #pragma unroll
            for (int rt = 0; rt < 3; ++rt) {
                bf16x8 ah = bzero(), al = bzero();
                if (g < 2) xfrag(x_pc + (pcb*NR + rt*16 + lr)*FEAT, g, ah, al);
                cp[rt] = MFMA(ah, bh, cp[rt]);
                cp[rt] = MFMA(al, bh, cp[rt]);
                cp[rt] = MFMA(ah, bl, cp[rt]);
            }
        }
        const float bbp = b_in_pc[colp];
        #pragma unroll
        for (int rt = 0; rt < 3; ++rt)
            #pragma unroll
            for (int r = 0; r < 4; ++r) {
                const int row = rt*16 + g*4 + r;
                float h = gelu_f(cp[rt][r] + bbp);
                *(float*)(Hp + row*512 + ((colp*4) ^ ((row&15)<<4))) = h;
            }
        f32x4 cr[3] = {z,z,z};
        {
            bf16x8 bh = *(const bf16x8*)(wb + OFF_WINSQ_H + (w*64 + lane)*8);
            bf16x8 bl = *(const bf16x8*)(wb + OFF_WINSQ_L + (w*64 + lane)*8);
            #pragma unroll
            for (int rt = 0; rt < 3; ++rt) {
                bf16x8 ah = bzero(), al = bzero();
                if (g < 2) {
                    int gr = rv_s[rt*16 + lr];
                    xfrag(x_sq + gr*FEAT, g, ah, al);
                }
                cr[rt] = MFMA(ah, bh, cr[rt]);
                cr[rt] = MFMA(al, bh, cr[rt]);
                cr[rt] = MFMA(ah, bl, cr[rt]);
            }
        }
        const float bbs = b_in_sq[colp];
        #pragma unroll
        for (int rt = 0; rt < 3; ++rt)
            #pragma unroll
            for (int r = 0; r < 4; ++r) {
                const int row0 = rt*16 + g*4 + r;
                const int dr = rv_d[row0];
                float h = gelu_f(cr[rt][r] + bbs);
                u16 hh, ll; split2(h, hh, ll);
                const int bo = dr*256 + ((colp*2) ^ ((dr&15)<<4));
                *(u16*)(Ah + bo) = hh;
                *(u16*)(Al + bo) = ll;
            }
    }
    __syncthreads();

    f32x4 c1[1][3];
    {
        const f32x4 z = {0.f,0.f,0.f,0.f};
        #pragma unroll
        for (int rt = 0; rt < 3; ++rt) c1[0][rt] = z;
    }
    gemm_nt<1,3>(Ah, Al, wb + OFF_WREV_H, wb + OFF_WREV_L, w, lane, g, lr, c1);
    __syncthreads();

    {
        const int d = t >> 3, cq8 = t & 7;
        if (d < NR) {
            float acc[16];
            #pragma unroll
            for (int i = 0; i < 16; ++i) acc[i] = 0.f;
            gather_f32_8(Hp, srt_a, rs_a[d], rs_a[d+1], cq8, acc);
            writeA_8(Ah, Al, d, cq8, acc);
        }
    }
    __syncthreads();

    gemm_nt<1,3>(Ah, Al, wb + OFF_WATT_H, wb + OFF_WATT_L, w, lane, g, lr, c1);
    __syncthreads();

    {
        const int d = t >> 3, cq8 = t & 7;
        if (d < NR) {
            float acc[16];
            #pragma unroll
            for (int i = 0; i < 16; ++i) acc[i] = 0.f;
            gather_f32_8(Hp, srt_d, rs_d[d], rs_d[d+1], cq8, acc);
            writeA_8(Ah, Al, d, cq8, acc);
        }
    }
    __syncthreads();

    gemm_nt<1,3>(Ah, Al, wb + OFF_WDEF_H, wb + OFF_WDEF_L, w, lane, g, lr, c1);
    __syncthreads();

    {
        const int colp = w*16 + lr;
        #pragma unroll
        for (int rt = 0; rt < 3; ++rt)
            #pragma unroll
            for (int r = 0; r < 4; ++r) {
                const int row = rt*16 + g*4 + r;
                float hvv = *(const float*)(Hp + row*512 + ((colp*4) ^ ((row&15)<<4)));
                float h2 = gelu_f(c1[0][rt][r] + hvv);
                u16 hh, ll; split2(h2, hh, ll);
                const int bo = row*256 + ((colp*2) ^ ((row&15)<<4));
                *(u16*)(Ah + bo) = hh;
                *(u16*)(Al + bo) = ll;
            }
    }
    __syncthreads();

    f32x4 c2[2][3];
    {
        const f32x4 z = {0.f,0.f,0.f,0.f};
        #pragma unroll
        for (int n = 0; n < 2; ++n)
            #pragma unroll
            for (int rt = 0; rt < 3; ++rt) c2[n][rt] = z;
    }
    gemm_nt<2,3>(Ah, Al, wb + OFF_WOUT_H, wb + OFF_WOUT_L, w*2, lane, g, lr, c2);
    #pragma unroll
    for (int ntl = 0; ntl < 2; ++ntl) {
        const int col = (w*2 + ntl)*16 + lr;
        const float bias = b_out[col];
        float s0 = 0.f, s1 = 0.f;
        #pragma unroll
        for (int r = 0; r < 4; ++r) s0 += gelu_f(c2[ntl][0][r] + bias);
        {
            float tt = 0.f;
            #pragma unroll
            for (int r = 0; r < 4; ++r) tt += gelu_f(c2[ntl][1][r] + bias);
            s0 += (g < 2) ? tt : 0.f;
            s1 += (g < 2) ? 0.f : tt;
        }
        #pragma unroll
        for (int r = 0; r < 4; ++r) s1 += gelu_f(c2[ntl][2][r] + bias);
        s0 += __shfl_xor(s0, 16); s0 += __shfl_xor(s0, 32);
        s1 += __shfl_xor(s1, 16); s1 += __shfl_xor(s1, 32);
        if (lane < 16) {
            const int b0 = pcb*2, b1 = b0 + 1;
            shared_pc[b0*DOUT + col] = s0 * (1.0f/PCN);
            shared_pc[b1*DOUT + col] = s1 * (1.0f/PCN);
        }
    }
}

// ---------------------------------------------------------------------------
__global__ __launch_bounds__(512, 4) void k_main(
    const float* __restrict__ x_sq, const float* __restrict__ x_pc,
    const float* __restrict__ b_in_sq, const float* __restrict__ b_in_pc,
    const float* __restrict__ b_out,
    const int* __restrict__ ei_adj, const int* __restrict__ ei_occ,
    const int* __restrict__ ei_att, const int* __restrict__ ei_def,
    const int* __restrict__ ei_rev,
    const u16* __restrict__ wb,
    float* __restrict__ shared_sq, float* __restrict__ shared_pc)
{
    extern __shared__ __align__(16) unsigned char SMb[];
    const int bid = blockIdx.x;
    const int grp = bid / 3, rem = bid - grp*3;
    if (rem < 2) {
        sq_path(SMb, grp*2 + rem, threadIdx.x, x_sq, x_pc, b_in_sq, b_in_pc,
                b_out, ei_adj, ei_occ, wb, shared_sq);
    } else {
        pc_path(SMb, grp, threadIdx.x, x_sq, x_pc, b_in_sq, b_in_pc,
                b_out, ei_att, ei_def, ei_rev, wb, shared_pc);
    }
}

// ---------------------------------------------------------------------------
__global__ __launch_bounds__(256) void k_head(
    const float* __restrict__ shared_sq, const float* __restrict__ shared_pc,
    const float* __restrict__ W_pt, const float* __restrict__ b_pt,
    const float* __restrict__ W_vt, const float* __restrict__ b_vt,
    const float* __restrict__ W_vh, const float* __restrict__ b_vh,
    u16* __restrict__ tpol_h, u16* __restrict__ tpol_l, float* __restrict__ out_value)
{
    __shared__ float sh[2*DOUT];
    __shared__ float vred[2*TDIM];
    const int t = threadIdx.x;
    const int hh = t >> 7, j = t & 127;
    const int b = blockIdx.x*2 + hh;
    for (int i = t; i < 2*DOUT; i += 256)
        sh[i] = shared_sq[blockIdx.x*2*DOUT + i] + shared_pc[blockIdx.x*2*DOUT + i];
    __syncthreads();
    const float* s = sh + hh*DOUT;
    float ap = b_pt[j], av = b_vt[j];
    #pragma unroll 8
    for (int k = 0; k < DOUT; ++k) {
        float sv = s[k];
        ap += sv * W_pt[k*TDIM + j];
        av += sv * W_vt[k*TDIM + j];
    }
    float tv = gelu_f(ap);
    u16 th, tl; split2(tv, th, tl);
    tpol_h[b*TDIM + j] = th;
    tpol_l[b*TDIM + j] = tl;
    vred[hh*TDIM + j] = gelu_f(av) * W_vh[j];
    __syncthreads();
    for (int stp = 64; stp > 0; stp >>= 1) {
        if (j < stp) vred[hh*TDIM + j] += vred[hh*TDIM + j + stp];
        __syncthreads();
    }
    if (j == 0) out_value[b] = tanhf(vred[hh*TDIM] + b_vh[0]);
}

// ---------------------------------------------------------------------------
__global__ __launch_bounds__(256) void k_pol(
    const u16* __restrict__ tpol_h, const u16* __restrict__ tpol_l,
    const u16* __restrict__ wb, const float* __restrict__ b_ph,
    float* __restrict__ pol)
{
    const u16* wph_h = wb + OFF_WPH_H;
    const u16* wph_l = wb + OFF_WPH_L;
    const int t = threadIdx.x, w = t >> 6, lane = t & 63, g = lane >> 4, lr = lane & 15;
    const int nt = blockIdx.x*4 + w;       // 0..291
    const int rbase = blockIdx.y*64;
    f32x4 acc[4];
    const f32x4 z = {0.f,0.f,0.f,0.f};
    #pragma unroll
    for (int rt = 0; rt < 4; ++rt) acc[rt] = z;
    #pragma unroll
    for (int ks = 0; ks < 4; ++ks) {
        bf16x8 bh = *(const bf16x8*)(wph_h + ((nt*4 + ks)*64 + lane)*8);
        bf16x8 bl = *(const bf16x8*)(wph_l + ((nt*4 + ks)*64 + lane)*8);
        #pragma unroll
        for (int rt = 0; rt < 4; ++rt) {
            const int ro = (rbase + rt*16 + lr)*TDIM + ks*32 + g*8;
            bf16x8 ah = *(const bf16x8*)(tpol_h + ro);
            bf16x8 al = *(const bf16x8*)(tpol_l + ro);
            acc[rt] = MFMA(ah, bh, acc[rt]);
            acc[rt] = MFMA(al, bh, acc[rt]);
            acc[rt] = MFMA(ah, bl, acc[rt]);
        }
    }
    const float bias = b_ph[nt*16 + lr];
    #pragma unroll
    for (int rt = 0; rt < 4; ++rt)
        #pragma unroll
        for (int r = 0; r < 4; ++r) {
            int row = rbase + rt*16 + g*4 + r;
            pol[(size_t)row*ADIM + nt*16 + lr] = acc[rt][r] + bias;
        }
}

// ---------------------------------------------------------------------------
extern "C" void kernel_launch(void* const* d_in, const int* in_sizes, int n_in,
                              void* d_out, int out_size, void* d_ws, size_t ws_size,
                              hipStream_t stream) {
    (void)in_sizes; (void)n_in; (void)out_size; (void)ws_size;
    const float* x_sq    = (const float*)d_in[0];
    const float* x_pc    = (const float*)d_in[1];
    const float* W_in_sq = (const float*)d_in[2];
    const float* b_in_sq = (const float*)d_in[3];
    const float* W_in_pc = (const float*)d_in[4];
    const float* b_in_pc = (const float*)d_in[5];
    const float* W_adj   = (const float*)d_in[6];
    const float* W_occ   = (const float*)d_in[7];
    const float* W_att   = (const float*)d_in[8];
    const float* W_def   = (const float*)d_in[9];
    const float* W_rev   = (const float*)d_in[10];
    const float* W_out   = (const float*)d_in[11];
    const float* b_out   = (const float*)d_in[12];
    const float* W_pt    = (const float*)d_in[13];
    const float* b_pt    = (const float*)d_in[14];
    const float* W_vt    = (const float*)d_in[15];
    const float* b_vt    = (const float*)d_in[16];
    const float* W_ph    = (const float*)d_in[17];
    const float* b_ph    = (const float*)d_in[18];
    const float* W_vh    = (const float*)d_in[19];
    const float* b_vh    = (const float*)d_in[20];
    const int* ei_adj    = (const int*)d_in[21];
    const int* ei_occ    = (const int*)d_in[22];
    const int* ei_att    = (const int*)d_in[23];
    const int* ei_def    = (const int*)d_in[24];
    const int* ei_rev    = (const int*)d_in[25];

    float* out = (float*)d_out;
    float* pol = out;
    float* val = out + (size_t)BATCH * ADIM;

    float* shared_sq = (float*)d_ws;                     // [2048][256] f32
    float* shared_pc = shared_sq + BATCH*DOUT;           // [2048][256] f32
    u16* tpol_h = (u16*)(shared_pc + BATCH*DOUT);        // [2048][128] bf16
    u16* tpol_l = tpol_h + BATCH*TDIM;
    u16* wb     = tpol_l + BATCH*TDIM;                   // WB_TOTAL u16

    hipFuncSetAttribute((const void*)k_main,
                        hipFuncAttributeMaxDynamicSharedMemorySize, K_SMEM);

    k_prep<<<352, 256, 0, stream>>>(W_adj, W_occ, W_att, W_def, W_rev, W_out, W_ph,
                                    W_in_sq, W_in_pc, wb);
    k_main<<<3072, 512, K_SMEM, stream>>>(x_sq, x_pc, b_in_sq, b_in_pc, b_out,
                                          ei_adj, ei_occ, ei_att, ei_def, ei_rev,
                                          wb, shared_sq, shared_pc);
    k_head<<<BATCH/2, 256, 0, stream>>>(shared_sq, shared_pc, W_pt, b_pt, W_vt, b_vt,
                                        W_vh, b_vh, tpol_h, tpol_l, val);
    k_pol<<<dim3(ADIM/64, BATCH/64), 256, 0, stream>>>(tpol_h, tpol_l, wb, b_ph, pol);
}